// Round 3
// baseline (221.090 us; speedup 1.0000x reference)
//
#include <hip/hip_runtime.h>
#include <hip/hip_bf16.h>
#include <stdint.h>

#define B_ 8
#define T_ 2304
#define DIN 1024
#define LAMBDA_INIT_F 0.6192834728526788f

typedef __bf16 bf16x8 __attribute__((ext_vector_type(8)));
typedef float f32x4 __attribute__((ext_vector_type(4)));

__device__ __forceinline__ unsigned short f2bf(float f) {
    union { float f; unsigned int u; } v; v.f = f;
    unsigned int u = v.u;
    unsigned int r = (u + 0x7FFFu + ((u >> 16) & 1u)) >> 16;
    return (unsigned short)r;
}

__device__ __forceinline__ unsigned int pack2bf(float lo, float hi) {
    return ((unsigned int)f2bf(hi) << 16) | (unsigned int)f2bf(lo);
}

// ---------------------------------------------------------------------------
// Kernel 1: transpose 9 weight mats (1024x128 f32) -> WT[seg][384][1024] bf16
// ---------------------------------------------------------------------------
__global__ __launch_bounds__(256) void k_wtrans(
    const float* w0, const float* w1, const float* w2,
    const float* w3, const float* w4, const float* w5,
    const float* w6, const float* w7, const float* w8,
    unsigned short* __restrict__ wt)
{
    __shared__ float tile[64][65];
    int bx = blockIdx.x;
    int mat = bx >> 5;
    int tl = bx & 31;
    int tx = tl & 15;      // k tile (0..15)
    int ty = tl >> 4;      // c tile (0..1)
    const float* srcs[9] = {w0, w1, w2, w3, w4, w5, w6, w7, w8};
    const float* src = srcs[mat];
    int k0 = tx * 64, c0 = ty * 64;
    int t = threadIdx.x;
    int r = t >> 2, cg = (t & 3) << 4;
    const float* p = src + (size_t)(k0 + r) * 128 + c0 + cg;
#pragma unroll
    for (int i = 0; i < 4; ++i) {
        float4 v = *(const float4*)(p + i * 4);
        tile[r][cg + i * 4 + 0] = v.x;
        tile[r][cg + i * 4 + 1] = v.y;
        tile[r][cg + i * 4 + 2] = v.z;
        tile[r][cg + i * 4 + 3] = v.w;
    }
    __syncthreads();
    int seg = mat / 3, m = mat % 3;
    int crow = seg * 384 + m * 128 + c0 + r;
    unsigned short* dst = wt + (size_t)crow * 1024 + k0 + cg;
    __align__(16) unsigned short ob[16];
#pragma unroll
    for (int i = 0; i < 16; ++i) ob[i] = f2bf(tile[cg + i][r]);
    *(uint4*)(dst) = *(const uint4*)(ob);
    *(uint4*)(dst + 8) = *(const uint4*)(ob + 8);
}

// ---------------------------------------------------------------------------
// Kernel 2: fused segment-LN + QKV projection.
// Block: 64 rows x 384 cols, 256 threads (4 waves), MFMA 16x16x32 bf16.
// Outputs: q,k [B][T][128] bf16 ; vT [B][128][T] bf16
// ---------------------------------------------------------------------------
__global__ __launch_bounds__(256) void k_proj(
    const float* __restrict__ x,
    const unsigned short* __restrict__ wt,
    const float* __restrict__ g_in, const float* __restrict__ b_in,
    const float* __restrict__ g_ss, const float* __restrict__ b_ss,
    const float* __restrict__ g_se, const float* __restrict__ b_se,
    unsigned short* __restrict__ qo,
    unsigned short* __restrict__ ko,
    unsigned short* __restrict__ vto)
{
    __shared__ unsigned short At[64 * 64];    // 8KB, rows of 128B, XOR-swizzled
    __shared__ unsigned short Wt[384 * 64];   // 48KB, rows of 128B, XOR-swizzled
    __shared__ float stats[64][2];

    int rt = blockIdx.x, b = blockIdx.y;
    int t0 = rt * 64;
    int seg = (rt < 2) ? 0 : ((rt < 34) ? 1 : 2);
    const float* gv = (seg == 0) ? g_ss : (seg == 1 ? g_in : g_se);
    const float* bv = (seg == 0) ? b_ss : (seg == 1 ? b_in : b_se);

    int tid = threadIdx.x;
    // LN stats: 4 threads per row
    {
        int r = tid >> 2, part = tid & 3;
        const float* xp = x + ((size_t)b * T_ + t0 + r) * DIN + part * 256;
        float s = 0.f, s2 = 0.f;
#pragma unroll 8
        for (int i = 0; i < 64; ++i) {
            float4 v = *(const float4*)(xp + i * 4);
            s += v.x + v.y + v.z + v.w;
            s2 += v.x * v.x + v.y * v.y + v.z * v.z + v.w * v.w;
        }
        s += __shfl_xor(s, 1);  s += __shfl_xor(s, 2);
        s2 += __shfl_xor(s2, 1); s2 += __shfl_xor(s2, 2);
        if (part == 0) {
            float mean = s * (1.f / 1024.f);
            float var = s2 * (1.f / 1024.f) - mean * mean;
            stats[r][0] = mean;
            stats[r][1] = rsqrtf(var + 1e-5f);
        }
    }
    __syncthreads();

    int w = tid >> 6, l = tid & 63;
    int wq = w * 96;
    f32x4 acc[4][6] = {};
    char* Ab = (char*)At;
    char* Wb = (char*)Wt;

    for (int ks = 0; ks < 16; ++ks) {
        int k0 = ks * 64;
        __syncthreads();
        // stage A (LN applied, bf16, swizzled)
        {
            int r = tid >> 2, cg = (tid & 3) << 4;
            const float* xp = x + ((size_t)b * T_ + t0 + r) * DIN + k0 + cg;
            float mean = stats[r][0], rs = stats[r][1];
            __align__(16) unsigned short tmp[16];
#pragma unroll
            for (int i = 0; i < 4; ++i) {
                float4 v = *(const float4*)(xp + i * 4);
                int kb = k0 + cg + i * 4;
                tmp[i * 4 + 0] = f2bf((v.x - mean) * rs * gv[kb + 0] + bv[kb + 0]);
                tmp[i * 4 + 1] = f2bf((v.y - mean) * rs * gv[kb + 1] + bv[kb + 1]);
                tmp[i * 4 + 2] = f2bf((v.z - mean) * rs * gv[kb + 2] + bv[kb + 2]);
                tmp[i * 4 + 3] = f2bf((v.w - mean) * rs * gv[kb + 3] + bv[kb + 3]);
            }
            int sw = (r & 7) << 4;
            *(uint4*)(Ab + r * 128 + ((cg * 2) ^ sw)) = *(const uint4*)(tmp);
            *(uint4*)(Ab + r * 128 + ((cg * 2 + 16) ^ sw)) = *(const uint4*)(tmp + 8);
        }
        // stage W^T tile (384 rows x 64 k, bf16, swizzled)
        {
            int u = tid & 7;
            int rbase = tid >> 3;
#pragma unroll
            for (int p = 0; p < 12; ++p) {
                int r2 = rbase + p * 32;
                const char* src = (const char*)(wt + ((size_t)(seg * 384 + r2) * 1024 + k0)) + u * 16;
                uint4 v = *(const uint4*)src;
                *(uint4*)(Wb + r2 * 128 + ((u * 16) ^ ((r2 & 7) << 4))) = v;
            }
        }
        __syncthreads();
#pragma unroll
        for (int kk = 0; kk < 2; ++kk) {
            bf16x8 af[4];
#pragma unroll
            for (int r4 = 0; r4 < 4; ++r4) {
                int rr = r4 * 16 + (l & 15);
                af[r4] = *(const bf16x8*)(Ab + rr * 128 + ((kk * 64 + ((l >> 4) * 16)) ^ ((rr & 7) << 4)));
            }
            bf16x8 bfr[6];
#pragma unroll
            for (int nt = 0; nt < 6; ++nt) {
                int c = wq + nt * 16 + (l & 15);
                bfr[nt] = *(const bf16x8*)(Wb + c * 128 + ((kk * 64 + ((l >> 4) * 16)) ^ ((c & 7) << 4)));
            }
#pragma unroll
            for (int r4 = 0; r4 < 4; ++r4)
#pragma unroll
                for (int nt = 0; nt < 6; ++nt)
                    acc[r4][nt] = __builtin_amdgcn_mfma_f32_16x16x32_bf16(af[r4], bfr[nt], acc[r4][nt], 0, 0, 0);
        }
    }
    // epilogue: C layout col=l&15, row=(l>>4)*4+reg
#pragma unroll
    for (int r4 = 0; r4 < 4; ++r4) {
        int tb = t0 + r4 * 16 + ((l >> 4) << 2);
#pragma unroll
        for (int nt = 0; nt < 6; ++nt) {
            int c = wq + nt * 16 + (l & 15);
            f32x4 a = acc[r4][nt];
            if (c < 128) {
#pragma unroll
                for (int g = 0; g < 4; ++g)
                    qo[((size_t)b * T_ + tb + g) * 128 + c] = f2bf(a[g]);
            } else if (c < 256) {
#pragma unroll
                for (int g = 0; g < 4; ++g)
                    ko[((size_t)b * T_ + tb + g) * 128 + (c - 128)] = f2bf(a[g]);
            } else {
                int cv = c - 256;
                __align__(8) unsigned short pk[4];
#pragma unroll
                for (int g = 0; g < 4; ++g) pk[g] = f2bf(a[g]);
                *(uint2*)(vto + ((size_t)b * 128 + cv) * T_ + tb) = *(const uint2*)pk;
            }
        }
    }
}

// ---------------------------------------------------------------------------
// Kernel 3: causal diff flash-attention + fused output LN.
// Swapped-operand + in-block KV-split:
//   8 waves: wave (qg, p) = (w&3, w>>2). qg owns 16 q rows; parity p
//   processes kv-tiles 2t+p. T14 async-stage (issue loads before compute,
//   ds_write after barrier). Parity halves merged in LDS at the end.
// ---------------------------------------------------------------------------
__global__ __launch_bounds__(512) void k_attn(
    const unsigned short* __restrict__ qp_,
    const unsigned short* __restrict__ kp_,
    const unsigned short* __restrict__ vp_,
    const float* __restrict__ lq1, const float* __restrict__ lq2,
    const float* __restrict__ lk1, const float* __restrict__ lk2,
    const float* __restrict__ g_out, const float* __restrict__ b_out,
    float* __restrict__ out)
{
    // 0..16KB: K buf p0 | 16..32KB: K buf p1 | 32..48KB: V buf p0 |
    // 48..64KB: V buf p1 | merge: O f32 [0..64KB) + m,l [64..68KB)
    __shared__ __align__(16) char smem[69632];

    int bid = blockIdx.x;
    int j = 35 - (bid >> 3);     // descending: long-diagonal tiles first
    int b = bid & 7;
    int t0 = j * 64;
    int tid = threadIdx.x;
    int w8 = tid >> 6;
    int qg = w8 & 3;             // q sub-tile within block
    int p  = w8 >> 2;            // kv parity
    int l = tid & 63;
    int g4 = l >> 4, q = l & 15;
    int q_g = t0 + qg * 16 + q;

    // Q B-fragments (held all kernel): B[k=d][col=q]
    bf16x8 qf[2][2];
#pragma unroll
    for (int br = 0; br < 2; ++br)
#pragma unroll
        for (int h = 0; h < 2; ++h)
            qf[br][h] = *(const bf16x8*)(qp_ + ((size_t)b * T_ + q_g) * 128 + br * 64 + h * 32 + g4 * 8);

    auto stageIssue = [&](int kt, uint4* kv) {
        int u = tid & 255;
        int rK = u >> 2, cK = (u & 3) << 6;
        const char* sK = (const char*)(kp_ + ((size_t)b * T_ + kt * 64 + rK) * 128) + cK;
        kv[0] = *(const uint4*)(sK);
        kv[1] = *(const uint4*)(sK + 16);
        kv[2] = *(const uint4*)(sK + 32);
        kv[3] = *(const uint4*)(sK + 48);
        int rV = u >> 1, cV = (u & 1) << 6;
        const char* sV = (const char*)(vp_ + ((size_t)b * 128 + rV) * T_ + kt * 64) + cV;
        kv[4] = *(const uint4*)(sV);
        kv[5] = *(const uint4*)(sV + 16);
        kv[6] = *(const uint4*)(sV + 32);
        kv[7] = *(const uint4*)(sV + 48);
    };
    auto stageWrite = [&](int grp, const uint4* kv) {
        int u = tid & 255;
        char* Kw = smem + grp * 16384;
        char* Vw = smem + 32768 + grp * 16384;
        int rK = u >> 2, cK = (u & 3) << 6, swK = (rK & 7) << 4;
#pragma unroll
        for (int i = 0; i < 4; ++i)
            *(uint4*)(Kw + rK * 256 + ((cK + i * 16) ^ swK)) = kv[i];
        int rV = u >> 1, cV = (u & 1) << 6, swV = (rV & 7) << 4;
#pragma unroll
        for (int i = 0; i < 4; ++i)
            *(uint4*)(Vw + rV * 128 + ((cV + i * 16) ^ swV)) = kv[4 + i];
    };

    // prologue: stage tiles 0 (threads 0-255) and 1 (threads 256-511)
    {
        int grp = tid >> 8;
        if (grp <= j) {
            uint4 kv[8];
            stageIssue(grp, kv);
            stageWrite(grp, kv);
        }
    }
    __syncthreads();

    float mrun[2] = {-1e30f, -1e30f};
    float lrun[2] = {0.f, 0.f};
    f32x4 oacc[2][8] = {};
    const char* Kb = smem + p * 16384;
    const char* Vb = smem + 32768 + p * 16384;

    int nph = (j >> 1) + 1;
    for (int t = 0; t < nph; ++t) {
        // T14: issue next-phase loads before compute
        int pf = 2 * (t + 1) + (tid >> 8);
        bool pfv = (pf <= j);
        uint4 kv[8];
        if (pfv) stageIssue(pf, kv);

        int kt = 2 * t + p;
        if (kt <= j) {
            bool diag = (kt == j);
            unsigned int pk[2][4][2];
#pragma unroll
            for (int br = 0; br < 2; ++br) {
                f32x4 s[4] = {};
                __builtin_amdgcn_s_setprio(1);
#pragma unroll
                for (int h = 0; h < 2; ++h) {
#pragma unroll
                    for (int t4 = 0; t4 < 4; ++t4) {
                        int rk = t4 * 16 + q;
                        bf16x8 kf = *(const bf16x8*)(Kb + rk * 256 + ((br * 128 + h * 64 + g4 * 16) ^ ((rk & 7) << 4)));
                        s[t4] = __builtin_amdgcn_mfma_f32_16x16x32_bf16(kf, qf[br][h], s[t4], 0, 0, 0);
                    }
                }
                __builtin_amdgcn_s_setprio(0);
                float sv[16];
                float mx = -1e30f;
#pragma unroll
                for (int t4 = 0; t4 < 4; ++t4)
#pragma unroll
                    for (int r = 0; r < 4; ++r) {
                        float v = s[t4][r] * 0.125f;
                        if (diag) {
                            int kv_g = kt * 64 + t4 * 16 + g4 * 4 + r;
                            if (kv_g > q_g) v = -1e30f;
                        }
                        sv[t4 * 4 + r] = v;
                        mx = fmaxf(mx, v);
                    }
                mx = fmaxf(mx, __shfl_xor(mx, 16));
                mx = fmaxf(mx, __shfl_xor(mx, 32));
                // T13 defer-max: skip rescale when max growth <= 8
                float mn;
                if (__all(mx <= mrun[br] + 8.f)) {
                    mn = mrun[br];
                } else {
                    mn = fmaxf(mrun[br], mx);
                    float sf = __expf(mrun[br] - mn);
                    mrun[br] = mn;
                    lrun[br] *= sf;
#pragma unroll
                    for (int dblk = 0; dblk < 8; ++dblk)
#pragma unroll
                        for (int r = 0; r < 4; ++r)
                            oacc[br][dblk][r] *= sf;
                }
                float pr[16];
                float rs = 0.f;
#pragma unroll
                for (int i = 0; i < 16; ++i) {
                    pr[i] = __expf(sv[i] - mn);
                    rs += pr[i];
                }
                rs += __shfl_xor(rs, 16);
                rs += __shfl_xor(rs, 32);
                lrun[br] += rs;
#pragma unroll
                for (int t4 = 0; t4 < 4; ++t4) {
                    pk[br][t4][0] = pack2bf(pr[t4 * 4 + 0], pr[t4 * 4 + 1]);
                    pk[br][t4][1] = pack2bf(pr[t4 * 4 + 2], pr[t4 * 4 + 3]);
                }
            }
            // PV: O^T += V^T @ P^T ; P^T B-frag via shfl repack
#pragma unroll
            for (int h = 0; h < 2; ++h) {
                bf16x8 pb[2];
                int s0 = q + (((g4 * 2) & 3) << 4);
                int s1 = q + (((g4 * 2 + 1) & 3) << 4);
                int sel = g4 >> 1;
#pragma unroll
                for (int br = 0; br < 2; ++br) {
                    unsigned int m0a = (unsigned int)__shfl((int)pk[br][2 * h][0], s0);
                    unsigned int m0b = (unsigned int)__shfl((int)pk[br][2 * h + 1][0], s0);
                    unsigned int m1a = (unsigned int)__shfl((int)pk[br][2 * h][1], s0);
                    unsigned int m1b = (unsigned int)__shfl((int)pk[br][2 * h + 1][1], s0);
                    unsigned int m2a = (unsigned int)__shfl((int)pk[br][2 * h][0], s1);
                    unsigned int m2b = (unsigned int)__shfl((int)pk[br][2 * h + 1][0], s1);
                    unsigned int m3a = (unsigned int)__shfl((int)pk[br][2 * h][1], s1);
                    unsigned int m3b = (unsigned int)__shfl((int)pk[br][2 * h + 1][1], s1);
                    union { unsigned int u[4]; bf16x8 v; } pu;
                    pu.u[0] = sel ? m0b : m0a;
                    pu.u[1] = sel ? m1b : m1a;
                    pu.u[2] = sel ? m2b : m2a;
                    pu.u[3] = sel ? m3b : m3a;
                    pb[br] = pu.v;
                }
                __builtin_amdgcn_s_setprio(1);
#pragma unroll
                for (int dblk = 0; dblk < 8; ++dblk) {
                    int rv = dblk * 16 + q;
                    bf16x8 vf = *(const bf16x8*)(Vb + rv * 128 + ((h * 64 + g4 * 16) ^ ((rv & 7) << 4)));
                    oacc[0][dblk] = __builtin_amdgcn_mfma_f32_16x16x32_bf16(vf, pb[0], oacc[0][dblk], 0, 0, 0);
                    oacc[1][dblk] = __builtin_amdgcn_mfma_f32_16x16x32_bf16(vf, pb[1], oacc[1][dblk], 0, 0, 0);
                }
                __builtin_amdgcn_s_setprio(0);
            }
        }
        __syncthreads();
        if (pfv) stageWrite(tid >> 8, kv);
        __syncthreads();
    }

    // ---- merge parity halves in LDS (reuses staging buffers) ----
    float* Osh = (float*)smem;                 // [qg][word 0..63][lane]
    float* Msh = (float*)(smem + 65536);       // [qg][lane][m0,l0,m1,l1]
    if (p == 1) {
        int base = qg * 4096 + l;
#pragma unroll
        for (int br = 0; br < 2; ++br)
#pragma unroll
            for (int dblk = 0; dblk < 8; ++dblk)
#pragma unroll
                for (int r = 0; r < 4; ++r)
                    Osh[base + (br * 32 + dblk * 4 + r) * 64] = oacc[br][dblk][r];
        float4 ml;
        ml.x = mrun[0]; ml.y = lrun[0]; ml.z = mrun[1]; ml.w = lrun[1];
        *(float4*)(Msh + (qg * 64 + l) * 4) = ml;
    }
    __syncthreads();
    if (p == 0) {
        float4 ml = *(const float4*)(Msh + (qg * 64 + l) * 4);
        float m1v[2] = {ml.x, ml.z}, l1v[2] = {ml.y, ml.w};
        float lfin[2], a0[2], a1[2];
#pragma unroll
        for (int br = 0; br < 2; ++br) {
            float mstar = fmaxf(mrun[br], m1v[br]);
            a0[br] = __expf(mrun[br] - mstar);
            a1[br] = __expf(m1v[br] - mstar);
            lfin[br] = a0[br] * lrun[br] + a1[br] * l1v[br];
        }
        int base = qg * 4096 + l;
#pragma unroll
        for (int br = 0; br < 2; ++br)
#pragma unroll
            for (int dblk = 0; dblk < 8; ++dblk)
#pragma unroll
                for (int r = 0; r < 4; ++r)
                    oacc[br][dblk][r] = a0[br] * oacc[br][dblk][r]
                        + a1[br] * Osh[base + (br * 32 + dblk * 4 + r) * 64];

        // lambda via wave reduce
        float pa = lq1[l] * lk1[l];
        float pb2 = lq2[l] * lk2[l];
#pragma unroll
        for (int off = 32; off >= 1; off >>= 1) {
            pa += __shfl_xor(pa, off);
            pb2 += __shfl_xor(pb2, off);
        }
        float lam = __expf(pa) - __expf(pb2) + LAMBDA_INIT_F;

        // epilogue: att = o1 - lam*o2, LN over 128 d, write f32
        float att[8][4];
        float sm = 0.f;
        float inv1 = 1.f / lfin[0], inv2 = 1.f / lfin[1];
#pragma unroll
        for (int dblk = 0; dblk < 8; ++dblk)
#pragma unroll
            for (int r = 0; r < 4; ++r) {
                float a = oacc[0][dblk][r] * inv1 - lam * (oacc[1][dblk][r] * inv2);
                att[dblk][r] = a;
                sm += a;
            }
        sm += __shfl_xor(sm, 16);
        sm += __shfl_xor(sm, 32);
        float mean = sm * (1.f / 128.f);
        float sv2 = 0.f;
#pragma unroll
        for (int dblk = 0; dblk < 8; ++dblk)
#pragma unroll
            for (int r = 0; r < 4; ++r) {
                float d = att[dblk][r] - mean;
                sv2 += d * d;
            }
        sv2 += __shfl_xor(sv2, 16);
        sv2 += __shfl_xor(sv2, 32);
        float rstd = rsqrtf(sv2 * (1.f / 128.f) + 1e-5f);

        float* orow = out + ((size_t)b * T_ + q_g) * 128;
#pragma unroll
        for (int dblk = 0; dblk < 8; ++dblk) {
            int d0 = dblk * 16 + g4 * 4;
            float4 o;
            o.x = (att[dblk][0] - mean) * rstd * g_out[d0 + 0] + b_out[d0 + 0];
            o.y = (att[dblk][1] - mean) * rstd * g_out[d0 + 1] + b_out[d0 + 1];
            o.z = (att[dblk][2] - mean) * rstd * g_out[d0 + 2] + b_out[d0 + 2];
            o.w = (att[dblk][3] - mean) * rstd * g_out[d0 + 3] + b_out[d0 + 3];
            *(float4*)(orow + d0) = o;
        }
    }
}

extern "C" void kernel_launch(void* const* d_in, const int* in_sizes, int n_in,
                              void* d_out, int out_size, void* d_ws, size_t ws_size,
                              hipStream_t stream) {
    (void)in_sizes; (void)n_in; (void)out_size; (void)ws_size;
    const float* x = (const float*)d_in[0];
    char* ws = (char*)d_ws;
    unsigned short* wt  = (unsigned short*)ws;                          // 2359296 B
    unsigned short* qo  = (unsigned short*)(ws + 2359296);              // 4718592 B
    unsigned short* ko  = (unsigned short*)(ws + 2359296 + 4718592);    // 4718592 B
    unsigned short* vto = (unsigned short*)(ws + 2359296 + 2 * 4718592);// 4718592 B

    hipLaunchKernelGGL(k_wtrans, dim3(288), dim3(256), 0, stream,
        (const float*)d_in[4], (const float*)d_in[5], (const float*)d_in[6],
        (const float*)d_in[1], (const float*)d_in[2], (const float*)d_in[3],
        (const float*)d_in[7], (const float*)d_in[8], (const float*)d_in[9], wt);

    hipLaunchKernelGGL(k_proj, dim3(36, 8), dim3(256), 0, stream,
        x, wt,
        (const float*)d_in[10], (const float*)d_in[11],
        (const float*)d_in[12], (const float*)d_in[13],
        (const float*)d_in[14], (const float*)d_in[15],
        qo, ko, vto);

    hipLaunchKernelGGL(k_attn, dim3(288), dim3(512), 0, stream,
        qo, ko, vto,
        (const float*)d_in[18], (const float*)d_in[19],
        (const float*)d_in[20], (const float*)d_in[21],
        (const float*)d_in[16], (const float*)d_in[17],
        (float*)d_out);
}

// Round 4
// 167.369 us; speedup vs baseline: 1.3210x; 1.3210x over previous
//
#include <hip/hip_runtime.h>
#include <hip/hip_bf16.h>
#include <stdint.h>

#define B_ 8
#define T_ 2304
#define DIN 1024
#define LAMBDA_INIT_F 0.6192834728526788f

typedef __bf16 bf16x8 __attribute__((ext_vector_type(8)));
typedef float f32x4 __attribute__((ext_vector_type(4)));

__device__ __forceinline__ unsigned short f2bf(float f) {
    union { float f; unsigned int u; } v; v.f = f;
    unsigned int u = v.u;
    unsigned int r = (u + 0x7FFFu + ((u >> 16) & 1u)) >> 16;
    return (unsigned short)r;
}

__device__ __forceinline__ unsigned int pack2bf(float lo, float hi) {
    return ((unsigned int)f2bf(hi) << 16) | (unsigned int)f2bf(lo);
}

// ---------------------------------------------------------------------------
// Kernel 1: transpose 9 weight mats (1024x128 f32) -> WT[seg][384][1024] bf16
// ---------------------------------------------------------------------------
__global__ __launch_bounds__(256) void k_wtrans(
    const float* w0, const float* w1, const float* w2,
    const float* w3, const float* w4, const float* w5,
    const float* w6, const float* w7, const float* w8,
    unsigned short* __restrict__ wt)
{
    __shared__ float tile[64][65];
    int bx = blockIdx.x;
    int mat = bx >> 5;
    int tl = bx & 31;
    int tx = tl & 15;      // k tile (0..15)
    int ty = tl >> 4;      // c tile (0..1)
    const float* srcs[9] = {w0, w1, w2, w3, w4, w5, w6, w7, w8};
    const float* src = srcs[mat];
    int k0 = tx * 64, c0 = ty * 64;
    int t = threadIdx.x;
    int r = t >> 2, cg = (t & 3) << 4;
    const float* p = src + (size_t)(k0 + r) * 128 + c0 + cg;
#pragma unroll
    for (int i = 0; i < 4; ++i) {
        float4 v = *(const float4*)(p + i * 4);
        tile[r][cg + i * 4 + 0] = v.x;
        tile[r][cg + i * 4 + 1] = v.y;
        tile[r][cg + i * 4 + 2] = v.z;
        tile[r][cg + i * 4 + 3] = v.w;
    }
    __syncthreads();
    int seg = mat / 3, m = mat % 3;
    int crow = seg * 384 + m * 128 + c0 + r;
    unsigned short* dst = wt + (size_t)crow * 1024 + k0 + cg;
    __align__(16) unsigned short ob[16];
#pragma unroll
    for (int i = 0; i < 16; ++i) ob[i] = f2bf(tile[cg + i][r]);
    *(uint4*)(dst) = *(const uint4*)(ob);
    *(uint4*)(dst + 8) = *(const uint4*)(ob + 8);
}

// ---------------------------------------------------------------------------
// Kernel 2: fused segment-LN + QKV projection.
// Block: 64 rows x 384 cols, 256 threads (4 waves), MFMA 16x16x32 bf16.
// Outputs: q,k [B][T][128] bf16 ; vT [B][128][T] bf16
// ---------------------------------------------------------------------------
__global__ __launch_bounds__(256) void k_proj(
    const float* __restrict__ x,
    const unsigned short* __restrict__ wt,
    const float* __restrict__ g_in, const float* __restrict__ b_in,
    const float* __restrict__ g_ss, const float* __restrict__ b_ss,
    const float* __restrict__ g_se, const float* __restrict__ b_se,
    unsigned short* __restrict__ qo,
    unsigned short* __restrict__ ko,
    unsigned short* __restrict__ vto)
{
    __shared__ unsigned short At[64 * 64];    // 8KB, rows of 128B, XOR-swizzled
    __shared__ unsigned short Wt[384 * 64];   // 48KB, rows of 128B, XOR-swizzled
    __shared__ float stats[64][2];

    int rt = blockIdx.x, b = blockIdx.y;
    int t0 = rt * 64;
    int seg = (rt < 2) ? 0 : ((rt < 34) ? 1 : 2);
    const float* gv = (seg == 0) ? g_ss : (seg == 1 ? g_in : g_se);
    const float* bv = (seg == 0) ? b_ss : (seg == 1 ? b_in : b_se);

    int tid = threadIdx.x;
    // LN stats: 4 threads per row
    {
        int r = tid >> 2, part = tid & 3;
        const float* xp = x + ((size_t)b * T_ + t0 + r) * DIN + part * 256;
        float s = 0.f, s2 = 0.f;
#pragma unroll 8
        for (int i = 0; i < 64; ++i) {
            float4 v = *(const float4*)(xp + i * 4);
            s += v.x + v.y + v.z + v.w;
            s2 += v.x * v.x + v.y * v.y + v.z * v.z + v.w * v.w;
        }
        s += __shfl_xor(s, 1);  s += __shfl_xor(s, 2);
        s2 += __shfl_xor(s2, 1); s2 += __shfl_xor(s2, 2);
        if (part == 0) {
            float mean = s * (1.f / 1024.f);
            float var = s2 * (1.f / 1024.f) - mean * mean;
            stats[r][0] = mean;
            stats[r][1] = rsqrtf(var + 1e-5f);
        }
    }
    __syncthreads();

    int w = tid >> 6, l = tid & 63;
    int wq = w * 96;
    f32x4 acc[4][6] = {};
    char* Ab = (char*)At;
    char* Wb = (char*)Wt;

    for (int ks = 0; ks < 16; ++ks) {
        int k0 = ks * 64;
        __syncthreads();
        // stage A (LN applied, bf16, swizzled)
        {
            int r = tid >> 2, cg = (tid & 3) << 4;
            const float* xp = x + ((size_t)b * T_ + t0 + r) * DIN + k0 + cg;
            float mean = stats[r][0], rs = stats[r][1];
            __align__(16) unsigned short tmp[16];
#pragma unroll
            for (int i = 0; i < 4; ++i) {
                float4 v = *(const float4*)(xp + i * 4);
                int kb = k0 + cg + i * 4;
                tmp[i * 4 + 0] = f2bf((v.x - mean) * rs * gv[kb + 0] + bv[kb + 0]);
                tmp[i * 4 + 1] = f2bf((v.y - mean) * rs * gv[kb + 1] + bv[kb + 1]);
                tmp[i * 4 + 2] = f2bf((v.z - mean) * rs * gv[kb + 2] + bv[kb + 2]);
                tmp[i * 4 + 3] = f2bf((v.w - mean) * rs * gv[kb + 3] + bv[kb + 3]);
            }
            int sw = (r & 7) << 4;
            *(uint4*)(Ab + r * 128 + ((cg * 2) ^ sw)) = *(const uint4*)(tmp);
            *(uint4*)(Ab + r * 128 + ((cg * 2 + 16) ^ sw)) = *(const uint4*)(tmp + 8);
        }
        // stage W^T tile (384 rows x 64 k, bf16, swizzled)
        {
            int u = tid & 7;
            int rbase = tid >> 3;
#pragma unroll
            for (int p = 0; p < 12; ++p) {
                int r2 = rbase + p * 32;
                const char* src = (const char*)(wt + ((size_t)(seg * 384 + r2) * 1024 + k0)) + u * 16;
                uint4 v = *(const uint4*)src;
                *(uint4*)(Wb + r2 * 128 + ((u * 16) ^ ((r2 & 7) << 4))) = v;
            }
        }
        __syncthreads();
#pragma unroll
        for (int kk = 0; kk < 2; ++kk) {
            bf16x8 af[4];
#pragma unroll
            for (int r4 = 0; r4 < 4; ++r4) {
                int rr = r4 * 16 + (l & 15);
                af[r4] = *(const bf16x8*)(Ab + rr * 128 + ((kk * 64 + ((l >> 4) * 16)) ^ ((rr & 7) << 4)));
            }
            bf16x8 bfr[6];
#pragma unroll
            for (int nt = 0; nt < 6; ++nt) {
                int c = wq + nt * 16 + (l & 15);
                bfr[nt] = *(const bf16x8*)(Wb + c * 128 + ((kk * 64 + ((l >> 4) * 16)) ^ ((c & 7) << 4)));
            }
#pragma unroll
            for (int r4 = 0; r4 < 4; ++r4)
#pragma unroll
                for (int nt = 0; nt < 6; ++nt)
                    acc[r4][nt] = __builtin_amdgcn_mfma_f32_16x16x32_bf16(af[r4], bfr[nt], acc[r4][nt], 0, 0, 0);
        }
    }
    // epilogue: C layout col=l&15, row=(l>>4)*4+reg
#pragma unroll
    for (int r4 = 0; r4 < 4; ++r4) {
        int tb = t0 + r4 * 16 + ((l >> 4) << 2);
#pragma unroll
        for (int nt = 0; nt < 6; ++nt) {
            int c = wq + nt * 16 + (l & 15);
            f32x4 a = acc[r4][nt];
            if (c < 128) {
#pragma unroll
                for (int g = 0; g < 4; ++g)
                    qo[((size_t)b * T_ + tb + g) * 128 + c] = f2bf(a[g]);
            } else if (c < 256) {
#pragma unroll
                for (int g = 0; g < 4; ++g)
                    ko[((size_t)b * T_ + tb + g) * 128 + (c - 128)] = f2bf(a[g]);
            } else {
                int cv = c - 256;
                __align__(8) unsigned short pk[4];
#pragma unroll
                for (int g = 0; g < 4; ++g) pk[g] = f2bf(a[g]);
                *(uint2*)(vto + ((size_t)b * 128 + cv) * T_ + tb) = *(const uint2*)pk;
            }
        }
    }
}

// ---------------------------------------------------------------------------
// Kernel 3: causal diff flash-attention + fused output LN.
// Swapped-operand + in-block KV-split, spill-free restage:
//   8 waves: wave (qg, p). qg owns 16 q rows; parity p does kv-tiles 2t+p.
//   T14 prefetch in NAMED uint4 registers (no address-taken arrays).
//   __launch_bounds__(512,2) -> 256-VGPR budget, no scratch.
// ---------------------------------------------------------------------------
__global__ __launch_bounds__(512, 2) void k_attn(
    const unsigned short* __restrict__ qp_,
    const unsigned short* __restrict__ kp_,
    const unsigned short* __restrict__ vp_,
    const float* __restrict__ lq1, const float* __restrict__ lq2,
    const float* __restrict__ lk1, const float* __restrict__ lk2,
    const float* __restrict__ g_out, const float* __restrict__ b_out,
    float* __restrict__ out)
{
    // 0..16KB: K buf p0 | 16..32KB: K buf p1 | 32..48KB: V buf p0 |
    // 48..64KB: V buf p1 | merge reuse: O f32 [0..64KB) + m,l [64..68KB)
    __shared__ __align__(16) char smem[69632];

    int bid = blockIdx.x;
    int j = 35 - (bid >> 3);     // descending: long-diagonal tiles first
    int b = bid & 7;
    int t0 = j * 64;
    int tid = threadIdx.x;
    int w8 = tid >> 6;
    int qg = w8 & 3;             // q sub-tile within block
    int p  = w8 >> 2;            // kv parity
    int l = tid & 63;
    int g4 = l >> 4, q = l & 15;
    int q_g = t0 + qg * 16 + q;
    int grp = tid >> 8;          // staging group (== prefetch parity)
    int u = tid & 255;

    // ---- loop-invariant staging addresses ----
    int rK = u >> 2, cK = (u & 3) << 6;
    const char* srcK0 = (const char*)(kp_ + ((size_t)b * T_ + rK) * 128) + cK;
    int rV = u >> 1, cV = (u & 1) << 6;
    const char* srcV0 = (const char*)(vp_ + ((size_t)b * 128 + rV) * T_) + cV;
    int swK = (rK & 7) << 4;
    char* KwB = smem + grp * 16384 + rK * 256;
    int oko0 = (cK +  0) ^ swK, oko1 = (cK + 16) ^ swK;
    int oko2 = (cK + 32) ^ swK, oko3 = (cK + 48) ^ swK;
    int swV = (rV & 7) << 4;
    char* VwB = smem + 32768 + grp * 16384 + rV * 128;
    int ovo0 = (cV +  0) ^ swV, ovo1 = (cV + 16) ^ swV;
    int ovo2 = (cV + 32) ^ swV, ovo3 = (cV + 48) ^ swV;

    // Q B-fragments (held all kernel): B[k=d][col=q]
    bf16x8 qf[2][2];
#pragma unroll
    for (int br = 0; br < 2; ++br)
#pragma unroll
        for (int h = 0; h < 2; ++h)
            qf[br][h] = *(const bf16x8*)(qp_ + ((size_t)b * T_ + q_g) * 128 + br * 64 + h * 32 + g4 * 8);

    // prologue: stage tile `grp` into buffer `grp`
    if (grp <= j) {
        const char* sK = srcK0 + (size_t)grp * 16384;
        uint4 ka0 = *(const uint4*)(sK);
        uint4 ka1 = *(const uint4*)(sK + 16);
        uint4 ka2 = *(const uint4*)(sK + 32);
        uint4 ka3 = *(const uint4*)(sK + 48);
        const char* sV = srcV0 + (size_t)grp * 128;
        uint4 va0 = *(const uint4*)(sV);
        uint4 va1 = *(const uint4*)(sV + 16);
        uint4 va2 = *(const uint4*)(sV + 32);
        uint4 va3 = *(const uint4*)(sV + 48);
        *(uint4*)(KwB + oko0) = ka0;
        *(uint4*)(KwB + oko1) = ka1;
        *(uint4*)(KwB + oko2) = ka2;
        *(uint4*)(KwB + oko3) = ka3;
        *(uint4*)(VwB + ovo0) = va0;
        *(uint4*)(VwB + ovo1) = va1;
        *(uint4*)(VwB + ovo2) = va2;
        *(uint4*)(VwB + ovo3) = va3;
    }
    __syncthreads();

    float mrun[2] = {-1e30f, -1e30f};
    float lrun[2] = {0.f, 0.f};
    f32x4 oacc[2][8] = {};
    const char* Kb = smem + p * 16384;
    const char* Vb = smem + 32768 + p * 16384;

    int nph = (j >> 1) + 1;
    for (int t = 0; t < nph; ++t) {
        // T14: issue next-phase loads into named registers before compute
        int pf = 2 * (t + 1) + grp;
        bool pfv = (pf <= j);
        uint4 ka0, ka1, ka2, ka3, va0, va1, va2, va3;
        if (pfv) {
            const char* sK = srcK0 + (size_t)pf * 16384;
            ka0 = *(const uint4*)(sK);
            ka1 = *(const uint4*)(sK + 16);
            ka2 = *(const uint4*)(sK + 32);
            ka3 = *(const uint4*)(sK + 48);
            const char* sV = srcV0 + (size_t)pf * 128;
            va0 = *(const uint4*)(sV);
            va1 = *(const uint4*)(sV + 16);
            va2 = *(const uint4*)(sV + 32);
            va3 = *(const uint4*)(sV + 48);
        }

        int kt = 2 * t + p;
        if (kt <= j) {
            bool diag = (kt == j);
            unsigned int pk[2][4][2];
#pragma unroll
            for (int br = 0; br < 2; ++br) {
                f32x4 s[4] = {};
                __builtin_amdgcn_s_setprio(1);
#pragma unroll
                for (int h = 0; h < 2; ++h) {
#pragma unroll
                    for (int t4 = 0; t4 < 4; ++t4) {
                        int rk = t4 * 16 + q;
                        bf16x8 kf = *(const bf16x8*)(Kb + rk * 256 + ((br * 128 + h * 64 + g4 * 16) ^ ((rk & 7) << 4)));
                        s[t4] = __builtin_amdgcn_mfma_f32_16x16x32_bf16(kf, qf[br][h], s[t4], 0, 0, 0);
                    }
                }
                __builtin_amdgcn_s_setprio(0);
                float sv[16];
                float mx = -1e30f;
#pragma unroll
                for (int t4 = 0; t4 < 4; ++t4)
#pragma unroll
                    for (int r = 0; r < 4; ++r) {
                        float v = s[t4][r] * 0.125f;
                        if (diag) {
                            int kv_g = kt * 64 + t4 * 16 + g4 * 4 + r;
                            if (kv_g > q_g) v = -1e30f;
                        }
                        sv[t4 * 4 + r] = v;
                        mx = fmaxf(mx, v);
                    }
                mx = fmaxf(mx, __shfl_xor(mx, 16));
                mx = fmaxf(mx, __shfl_xor(mx, 32));
                // T13 defer-max: skip rescale when max growth <= 8
                float mn;
                if (__all(mx <= mrun[br] + 8.f)) {
                    mn = mrun[br];
                } else {
                    mn = fmaxf(mrun[br], mx);
                    float sf = __expf(mrun[br] - mn);
                    mrun[br] = mn;
                    lrun[br] *= sf;
#pragma unroll
                    for (int dblk = 0; dblk < 8; ++dblk)
#pragma unroll
                        for (int r = 0; r < 4; ++r)
                            oacc[br][dblk][r] *= sf;
                }
                float pr[16];
                float rs = 0.f;
#pragma unroll
                for (int i = 0; i < 16; ++i) {
                    pr[i] = __expf(sv[i] - mn);
                    rs += pr[i];
                }
                rs += __shfl_xor(rs, 16);
                rs += __shfl_xor(rs, 32);
                lrun[br] += rs;
#pragma unroll
                for (int t4 = 0; t4 < 4; ++t4) {
                    pk[br][t4][0] = pack2bf(pr[t4 * 4 + 0], pr[t4 * 4 + 1]);
                    pk[br][t4][1] = pack2bf(pr[t4 * 4 + 2], pr[t4 * 4 + 3]);
                }
            }
            // PV: O^T += V^T @ P^T ; P^T B-frag via shfl repack
#pragma unroll
            for (int h = 0; h < 2; ++h) {
                bf16x8 pb[2];
                int s0 = q + (((g4 * 2) & 3) << 4);
                int s1 = q + (((g4 * 2 + 1) & 3) << 4);
                int sel = g4 >> 1;
#pragma unroll
                for (int br = 0; br < 2; ++br) {
                    unsigned int m0a = (unsigned int)__shfl((int)pk[br][2 * h][0], s0);
                    unsigned int m0b = (unsigned int)__shfl((int)pk[br][2 * h + 1][0], s0);
                    unsigned int m1a = (unsigned int)__shfl((int)pk[br][2 * h][1], s0);
                    unsigned int m1b = (unsigned int)__shfl((int)pk[br][2 * h + 1][1], s0);
                    unsigned int m2a = (unsigned int)__shfl((int)pk[br][2 * h][0], s1);
                    unsigned int m2b = (unsigned int)__shfl((int)pk[br][2 * h + 1][0], s1);
                    unsigned int m3a = (unsigned int)__shfl((int)pk[br][2 * h][1], s1);
                    unsigned int m3b = (unsigned int)__shfl((int)pk[br][2 * h + 1][1], s1);
                    union { unsigned int uu[4]; bf16x8 v; } pu;
                    pu.uu[0] = sel ? m0b : m0a;
                    pu.uu[1] = sel ? m1b : m1a;
                    pu.uu[2] = sel ? m2b : m2a;
                    pu.uu[3] = sel ? m3b : m3a;
                    pb[br] = pu.v;
                }
                __builtin_amdgcn_s_setprio(1);
#pragma unroll
                for (int dblk = 0; dblk < 8; ++dblk) {
                    int rv = dblk * 16 + q;
                    bf16x8 vf = *(const bf16x8*)(Vb + rv * 128 + ((h * 64 + g4 * 16) ^ ((rv & 7) << 4)));
                    oacc[0][dblk] = __builtin_amdgcn_mfma_f32_16x16x32_bf16(vf, pb[0], oacc[0][dblk], 0, 0, 0);
                    oacc[1][dblk] = __builtin_amdgcn_mfma_f32_16x16x32_bf16(vf, pb[1], oacc[1][dblk], 0, 0, 0);
                }
                __builtin_amdgcn_s_setprio(0);
            }
        }
        __syncthreads();
        if (pfv) {
            *(uint4*)(KwB + oko0) = ka0;
            *(uint4*)(KwB + oko1) = ka1;
            *(uint4*)(KwB + oko2) = ka2;
            *(uint4*)(KwB + oko3) = ka3;
            *(uint4*)(VwB + ovo0) = va0;
            *(uint4*)(VwB + ovo1) = va1;
            *(uint4*)(VwB + ovo2) = va2;
            *(uint4*)(VwB + ovo3) = va3;
        }
        __syncthreads();
    }

    // ---- merge parity halves in LDS (reuses staging buffers) ----
    float* Osh = (float*)smem;                 // [qg][word 0..63][lane]
    float* Msh = (float*)(smem + 65536);       // [qg][lane][m0,l0,m1,l1]
    if (p == 1) {
        int base = qg * 4096 + l;
#pragma unroll
        for (int br = 0; br < 2; ++br)
#pragma unroll
            for (int dblk = 0; dblk < 8; ++dblk)
#pragma unroll
                for (int r = 0; r < 4; ++r)
                    Osh[base + (br * 32 + dblk * 4 + r) * 64] = oacc[br][dblk][r];
        float4 ml;
        ml.x = mrun[0]; ml.y = lrun[0]; ml.z = mrun[1]; ml.w = lrun[1];
        *(float4*)(Msh + (qg * 64 + l) * 4) = ml;
    }
    __syncthreads();
    if (p == 0) {
        float4 ml = *(const float4*)(Msh + (qg * 64 + l) * 4);
        float m1v[2] = {ml.x, ml.z}, l1v[2] = {ml.y, ml.w};
        float lfin[2], a0[2], a1[2];
#pragma unroll
        for (int br = 0; br < 2; ++br) {
            float mstar = fmaxf(mrun[br], m1v[br]);
            a0[br] = __expf(mrun[br] - mstar);
            a1[br] = __expf(m1v[br] - mstar);
            lfin[br] = a0[br] * lrun[br] + a1[br] * l1v[br];
        }
        int base = qg * 4096 + l;
#pragma unroll
        for (int br = 0; br < 2; ++br)
#pragma unroll
            for (int dblk = 0; dblk < 8; ++dblk)
#pragma unroll
                for (int r = 0; r < 4; ++r)
                    oacc[br][dblk][r] = a0[br] * oacc[br][dblk][r]
                        + a1[br] * Osh[base + (br * 32 + dblk * 4 + r) * 64];

        // lambda via wave reduce
        float pa = lq1[l] * lk1[l];
        float pb2 = lq2[l] * lk2[l];
#pragma unroll
        for (int off = 32; off >= 1; off >>= 1) {
            pa += __shfl_xor(pa, off);
            pb2 += __shfl_xor(pb2, off);
        }
        float lam = __expf(pa) - __expf(pb2) + LAMBDA_INIT_F;

        // epilogue: att = o1 - lam*o2, LN over 128 d, write f32
        float att[8][4];
        float sm = 0.f;
        float inv1 = 1.f / lfin[0], inv2 = 1.f / lfin[1];
#pragma unroll
        for (int dblk = 0; dblk < 8; ++dblk)
#pragma unroll
            for (int r = 0; r < 4; ++r) {
                float a = oacc[0][dblk][r] * inv1 - lam * (oacc[1][dblk][r] * inv2);
                att[dblk][r] = a;
                sm += a;
            }
        sm += __shfl_xor(sm, 16);
        sm += __shfl_xor(sm, 32);
        float mean = sm * (1.f / 128.f);
        float sv2 = 0.f;
#pragma unroll
        for (int dblk = 0; dblk < 8; ++dblk)
#pragma unroll
            for (int r = 0; r < 4; ++r) {
                float d = att[dblk][r] - mean;
                sv2 += d * d;
            }
        sv2 += __shfl_xor(sv2, 16);
        sv2 += __shfl_xor(sv2, 32);
        float rstd = rsqrtf(sv2 * (1.f / 128.f) + 1e-5f);

        float* orow = out + ((size_t)b * T_ + q_g) * 128;
#pragma unroll
        for (int dblk = 0; dblk < 8; ++dblk) {
            int d0 = dblk * 16 + g4 * 4;
            float4 o;
            o.x = (att[dblk][0] - mean) * rstd * g_out[d0 + 0] + b_out[d0 + 0];
            o.y = (att[dblk][1] - mean) * rstd * g_out[d0 + 1] + b_out[d0 + 1];
            o.z = (att[dblk][2] - mean) * rstd * g_out[d0 + 2] + b_out[d0 + 2];
            o.w = (att[dblk][3] - mean) * rstd * g_out[d0 + 3] + b_out[d0 + 3];
            *(float4*)(orow + d0) = o;
        }
    }
}

extern "C" void kernel_launch(void* const* d_in, const int* in_sizes, int n_in,
                              void* d_out, int out_size, void* d_ws, size_t ws_size,
                              hipStream_t stream) {
    (void)in_sizes; (void)n_in; (void)out_size; (void)ws_size;
    const float* x = (const float*)d_in[0];
    char* ws = (char*)d_ws;
    unsigned short* wt  = (unsigned short*)ws;                          // 2359296 B
    unsigned short* qo  = (unsigned short*)(ws + 2359296);              // 4718592 B
    unsigned short* ko  = (unsigned short*)(ws + 2359296 + 4718592);    // 4718592 B
    unsigned short* vto = (unsigned short*)(ws + 2359296 + 2 * 4718592);// 4718592 B

    hipLaunchKernelGGL(k_wtrans, dim3(288), dim3(256), 0, stream,
        (const float*)d_in[4], (const float*)d_in[5], (const float*)d_in[6],
        (const float*)d_in[1], (const float*)d_in[2], (const float*)d_in[3],
        (const float*)d_in[7], (const float*)d_in[8], (const float*)d_in[9], wt);

    hipLaunchKernelGGL(k_proj, dim3(36, 8), dim3(256), 0, stream,
        x, wt,
        (const float*)d_in[10], (const float*)d_in[11],
        (const float*)d_in[12], (const float*)d_in[13],
        (const float*)d_in[14], (const float*)d_in[15],
        qo, ko, vto);

    hipLaunchKernelGGL(k_attn, dim3(288), dim3(512), 0, stream,
        qo, ko, vto,
        (const float*)d_in[18], (const float*)d_in[19],
        (const float*)d_in[20], (const float*)d_in[21],
        (const float*)d_in[16], (const float*)d_in[17],
        (float*)d_out);
}

// Round 5
// 131.161 us; speedup vs baseline: 1.6856x; 1.2761x over previous
//
#include <hip/hip_runtime.h>
#include <hip/hip_bf16.h>
#include <stdint.h>

#define B_ 8
#define T_ 2304
#define DIN 1024
#define LAMBDA_INIT_F 0.6192834728526788f

typedef __bf16 bf16x8 __attribute__((ext_vector_type(8)));
typedef float f32x4 __attribute__((ext_vector_type(4)));

__device__ __forceinline__ unsigned short f2bf(float f) {
    union { float f; unsigned int u; } v; v.f = f;
    unsigned int u = v.u;
    unsigned int r = (u + 0x7FFFu + ((u >> 16) & 1u)) >> 16;
    return (unsigned short)r;
}

__device__ __forceinline__ unsigned int pack2bf(float lo, float hi) {
    return ((unsigned int)f2bf(hi) << 16) | (unsigned int)f2bf(lo);
}

// ---------------------------------------------------------------------------
// Kernel 1: transpose 9 weight mats (1024x128 f32) -> WT[seg][384][1024] bf16
// ---------------------------------------------------------------------------
__global__ __launch_bounds__(256) void k_wtrans(
    const float* w0, const float* w1, const float* w2,
    const float* w3, const float* w4, const float* w5,
    const float* w6, const float* w7, const float* w8,
    unsigned short* __restrict__ wt)
{
    __shared__ float tile[64][65];
    int bx = blockIdx.x;
    int mat = bx >> 5;
    int tl = bx & 31;
    int tx = tl & 15;
    int ty = tl >> 4;
    const float* srcs[9] = {w0, w1, w2, w3, w4, w5, w6, w7, w8};
    const float* src = srcs[mat];
    int k0 = tx * 64, c0 = ty * 64;
    int t = threadIdx.x;
    int r = t >> 2, cg = (t & 3) << 4;
    const float* p = src + (size_t)(k0 + r) * 128 + c0 + cg;
#pragma unroll
    for (int i = 0; i < 4; ++i) {
        float4 v = *(const float4*)(p + i * 4);
        tile[r][cg + i * 4 + 0] = v.x;
        tile[r][cg + i * 4 + 1] = v.y;
        tile[r][cg + i * 4 + 2] = v.z;
        tile[r][cg + i * 4 + 3] = v.w;
    }
    __syncthreads();
    int seg = mat / 3, m = mat % 3;
    int crow = seg * 384 + m * 128 + c0 + r;
    unsigned short* dst = wt + (size_t)crow * 1024 + k0 + cg;
    __align__(16) unsigned short ob[16];
#pragma unroll
    for (int i = 0; i < 16; ++i) ob[i] = f2bf(tile[cg + i][r]);
    *(uint4*)(dst) = *(const uint4*)(ob);
    *(uint4*)(dst + 8) = *(const uint4*)(ob + 8);
}

// ---------------------------------------------------------------------------
// Kernel 2: streaming LayerNorm: x f32 -> xbf bf16 [18432][1024].
// One row per wave, 4 waves/block, fully vectorized.
// ---------------------------------------------------------------------------
__global__ __launch_bounds__(256) void k_ln(
    const float* __restrict__ x,
    const float* __restrict__ g_in, const float* __restrict__ b_in,
    const float* __restrict__ g_ss, const float* __restrict__ b_ss,
    const float* __restrict__ g_se, const float* __restrict__ b_se,
    unsigned short* __restrict__ xbf)
{
    int row = (blockIdx.x << 2) + (threadIdx.x >> 6);
    int l = threadIdx.x & 63;
    int t = row % T_;
    const float* gv; const float* bv;
    if (t < 128)       { gv = g_ss; bv = b_ss; }
    else if (t < 2176) { gv = g_in; bv = b_in; }
    else               { gv = g_se; bv = b_se; }
    const float* xp = x + (size_t)row * DIN + l * 4;
    float4 v0 = *(const float4*)(xp);
    float4 v1 = *(const float4*)(xp + 256);
    float4 v2 = *(const float4*)(xp + 512);
    float4 v3 = *(const float4*)(xp + 768);
    float s  = v0.x + v0.y + v0.z + v0.w + v1.x + v1.y + v1.z + v1.w
             + v2.x + v2.y + v2.z + v2.w + v3.x + v3.y + v3.z + v3.w;
    float s2 = v0.x*v0.x + v0.y*v0.y + v0.z*v0.z + v0.w*v0.w
             + v1.x*v1.x + v1.y*v1.y + v1.z*v1.z + v1.w*v1.w
             + v2.x*v2.x + v2.y*v2.y + v2.z*v2.z + v2.w*v2.w
             + v3.x*v3.x + v3.y*v3.y + v3.z*v3.z + v3.w*v3.w;
#pragma unroll
    for (int off = 1; off <= 32; off <<= 1) {
        s  += __shfl_xor(s,  off);
        s2 += __shfl_xor(s2, off);
    }
    float mean = s * (1.f / 1024.f);
    float rstd = rsqrtf(s2 * (1.f / 1024.f) - mean * mean + 1e-5f);
    unsigned short* op = xbf + (size_t)row * DIN + l * 4;
    const float* gp = gv + l * 4;
    const float* bp = bv + l * 4;
#pragma unroll
    for (int k = 0; k < 4; ++k) {
        float4 vv = (k == 0) ? v0 : (k == 1) ? v1 : (k == 2) ? v2 : v3;
        float4 gk = *(const float4*)(gp + k * 256);
        float4 bk = *(const float4*)(bp + k * 256);
        uint2 o;
        o.x = pack2bf((vv.x - mean) * rstd * gk.x + bk.x,
                      (vv.y - mean) * rstd * gk.y + bk.y);
        o.y = pack2bf((vv.z - mean) * rstd * gk.z + bk.z,
                      (vv.w - mean) * rstd * gk.w + bk.w);
        *(uint2*)(op + k * 256) = o;
    }
}

// ---------------------------------------------------------------------------
// Kernel 3: pure bf16 GEMM: C[18432][384] = xbf @ wt[seg]^T.
// Block: 128 rows x 192 cols (ch selects N-half), 512 threads (8 waves 2x4).
// Double-buffered LDS (80KB) + named-register prefetch of next K-step.
// Outputs: q,k [18432][128] bf16 ; vT [B][128][T] bf16
// ---------------------------------------------------------------------------
__global__ __launch_bounds__(512, 4) void k_proj2(
    const unsigned short* __restrict__ xbf,
    const unsigned short* __restrict__ wt,
    unsigned short* __restrict__ qo,
    unsigned short* __restrict__ ko,
    unsigned short* __restrict__ vto)
{
    // A: [0,16K)+[16K,32K) dbuf; W: [32K,56K)+[56K,80K) dbuf
    __shared__ __align__(16) char smem[81920];

    int bid = blockIdx.x;
    int mt = bid >> 1, ch = bid & 1;
    int bb = mt / 18, tt = mt % 18;
    int seg = (tt == 0) ? 0 : ((tt < 17) ? 1 : 2);
    size_t arow0 = (size_t)mt * 128;
    int ncol0 = ch * 192;
    int wrow0 = seg * 384 + ncol0;

    int tid = threadIdx.x;
    int w = tid >> 6, l = tid & 63;
    int wr = w >> 2, wc = w & 3;
    int g4 = l >> 4, cr = l & 15;

    // ---- staging map (loop-invariant) ----
    int rA0 = tid >> 3, cS = (tid & 7) << 4;
    const char* srcA0 = (const char*)xbf + (arow0 + rA0) * 2048 + cS;
    const char* srcA1 = srcA0 + (size_t)64 * 2048;
    int dA0 = rA0 * 128 + (cS ^ ((rA0 & 7) << 4));
    int dA1 = dA0 + 64 * 128;
    const char* srcW0 = (const char*)wt + (size_t)(wrow0 + rA0) * 2048 + cS;
    const char* srcW1 = srcW0 + (size_t)64 * 2048;
    const char* srcW2 = srcW0 + (size_t)128 * 2048;
    int dW0 = dA0, dW1 = dA0 + 64 * 128, dW2 = dA0 + 128 * 128;

    // prologue: stage k-step 0 into buffer 0
    {
        uint4 a0 = *(const uint4*)srcA0;
        uint4 a1 = *(const uint4*)srcA1;
        uint4 w0 = *(const uint4*)srcW0;
        uint4 w1 = *(const uint4*)srcW1;
        uint4 w2 = *(const uint4*)srcW2;
        *(uint4*)(smem + dA0) = a0;
        *(uint4*)(smem + dA1) = a1;
        *(uint4*)(smem + 32768 + dW0) = w0;
        *(uint4*)(smem + 32768 + dW1) = w1;
        *(uint4*)(smem + 32768 + dW2) = w2;
    }
    __syncthreads();

    f32x4 acc[4][3] = {};
    for (int ks = 0; ks < 16; ++ks) {
        bool pf = (ks < 15);
        uint4 pa0, pa1, pw0, pw1, pw2;
        if (pf) {
            size_t o = (size_t)(ks + 1) * 128;
            pa0 = *(const uint4*)(srcA0 + o);
            pa1 = *(const uint4*)(srcA1 + o);
            pw0 = *(const uint4*)(srcW0 + o);
            pw1 = *(const uint4*)(srcW1 + o);
            pw2 = *(const uint4*)(srcW2 + o);
        }
        const char* Ab = smem + (ks & 1) * 16384;
        const char* Wb = smem + 32768 + (ks & 1) * 24576;
        __builtin_amdgcn_s_setprio(1);
#pragma unroll
        for (int kk = 0; kk < 2; ++kk) {
            int kb = kk * 64 + g4 * 16;
            bf16x8 af[4];
#pragma unroll
            for (int r4 = 0; r4 < 4; ++r4) {
                int rr = wr * 64 + r4 * 16 + cr;
                af[r4] = *(const bf16x8*)(Ab + rr * 128 + (kb ^ ((rr & 7) << 4)));
            }
            bf16x8 bfr[3];
#pragma unroll
            for (int nt = 0; nt < 3; ++nt) {
                int c = wc * 48 + nt * 16 + cr;
                bfr[nt] = *(const bf16x8*)(Wb + c * 128 + (kb ^ ((c & 7) << 4)));
            }
#pragma unroll
            for (int r4 = 0; r4 < 4; ++r4)
#pragma unroll
                for (int nt = 0; nt < 3; ++nt)
                    acc[r4][nt] = __builtin_amdgcn_mfma_f32_16x16x32_bf16(af[r4], bfr[nt], acc[r4][nt], 0, 0, 0);
        }
        __builtin_amdgcn_s_setprio(0);
        __syncthreads();
        if (pf) {
            char* An = smem + ((ks + 1) & 1) * 16384;
            char* Wn = smem + 32768 + ((ks + 1) & 1) * 24576;
            *(uint4*)(An + dA0) = pa0;
            *(uint4*)(An + dA1) = pa1;
            *(uint4*)(Wn + dW0) = pw0;
            *(uint4*)(Wn + dW1) = pw1;
            *(uint4*)(Wn + dW2) = pw2;
        }
        __syncthreads();
    }

    // epilogue: C layout col=cr, row=(g4*4+g) within each 16x16 tile
#pragma unroll
    for (int r4 = 0; r4 < 4; ++r4) {
        size_t grow = arow0 + wr * 64 + r4 * 16 + g4 * 4;
#pragma unroll
        for (int nt = 0; nt < 3; ++nt) {
            int c = ncol0 + wc * 48 + nt * 16 + cr;
            f32x4 a = acc[r4][nt];
            if (c < 128) {
#pragma unroll
                for (int g = 0; g < 4; ++g)
                    qo[(grow + g) * 128 + c] = f2bf(a[g]);
            } else if (c < 256) {
#pragma unroll
                for (int g = 0; g < 4; ++g)
                    ko[(grow + g) * 128 + (c - 128)] = f2bf(a[g]);
            } else {
                int cv = c - 256;
                int trow = tt * 128 + wr * 64 + r4 * 16 + g4 * 4;
                uint2 o;
                o.x = pack2bf(a[0], a[1]);
                o.y = pack2bf(a[2], a[3]);
                *(uint2*)(vto + ((size_t)bb * 128 + cv) * T_ + trow) = o;
            }
        }
    }
}

// ---------------------------------------------------------------------------
// Kernel 4: causal diff flash-attention + fused output LN (unchanged R4).
// ---------------------------------------------------------------------------
__global__ __launch_bounds__(512, 2) void k_attn(
    const unsigned short* __restrict__ qp_,
    const unsigned short* __restrict__ kp_,
    const unsigned short* __restrict__ vp_,
    const float* __restrict__ lq1, const float* __restrict__ lq2,
    const float* __restrict__ lk1, const float* __restrict__ lk2,
    const float* __restrict__ g_out, const float* __restrict__ b_out,
    float* __restrict__ out)
{
    __shared__ __align__(16) char smem[69632];

    int bid = blockIdx.x;
    int j = 35 - (bid >> 3);
    int b = bid & 7;
    int t0 = j * 64;
    int tid = threadIdx.x;
    int w8 = tid >> 6;
    int qg = w8 & 3;
    int p  = w8 >> 2;
    int l = tid & 63;
    int g4 = l >> 4, q = l & 15;
    int q_g = t0 + qg * 16 + q;
    int grp = tid >> 8;
    int u = tid & 255;

    int rK = u >> 2, cK = (u & 3) << 6;
    const char* srcK0 = (const char*)(kp_ + ((size_t)b * T_ + rK) * 128) + cK;
    int rV = u >> 1, cV = (u & 1) << 6;
    const char* srcV0 = (const char*)(vp_ + ((size_t)b * 128 + rV) * T_) + cV;
    int swK = (rK & 7) << 4;
    char* KwB = smem + grp * 16384 + rK * 256;
    int oko0 = (cK +  0) ^ swK, oko1 = (cK + 16) ^ swK;
    int oko2 = (cK + 32) ^ swK, oko3 = (cK + 48) ^ swK;
    int swV = (rV & 7) << 4;
    char* VwB = smem + 32768 + grp * 16384 + rV * 128;
    int ovo0 = (cV +  0) ^ swV, ovo1 = (cV + 16) ^ swV;
    int ovo2 = (cV + 32) ^ swV, ovo3 = (cV + 48) ^ swV;

    bf16x8 qf[2][2];
#pragma unroll
    for (int br = 0; br < 2; ++br)
#pragma unroll
        for (int h = 0; h < 2; ++h)
            qf[br][h] = *(const bf16x8*)(qp_ + ((size_t)b * T_ + q_g) * 128 + br * 64 + h * 32 + g4 * 8);

    if (grp <= j) {
        const char* sK = srcK0 + (size_t)grp * 16384;
        uint4 ka0 = *(const uint4*)(sK);
        uint4 ka1 = *(const uint4*)(sK + 16);
        uint4 ka2 = *(const uint4*)(sK + 32);
        uint4 ka3 = *(const uint4*)(sK + 48);
        const char* sV = srcV0 + (size_t)grp * 128;
        uint4 va0 = *(const uint4*)(sV);
        uint4 va1 = *(const uint4*)(sV + 16);
        uint4 va2 = *(const uint4*)(sV + 32);
        uint4 va3 = *(const uint4*)(sV + 48);
        *(uint4*)(KwB + oko0) = ka0;
        *(uint4*)(KwB + oko1) = ka1;
        *(uint4*)(KwB + oko2) = ka2;
        *(uint4*)(KwB + oko3) = ka3;
        *(uint4*)(VwB + ovo0) = va0;
        *(uint4*)(VwB + ovo1) = va1;
        *(uint4*)(VwB + ovo2) = va2;
        *(uint4*)(VwB + ovo3) = va3;
    }
    __syncthreads();

    float mrun[2] = {-1e30f, -1e30f};
    float lrun[2] = {0.f, 0.f};
    f32x4 oacc[2][8] = {};
    const char* Kb = smem + p * 16384;
    const char* Vb = smem + 32768 + p * 16384;

    int nph = (j >> 1) + 1;
    for (int t = 0; t < nph; ++t) {
        int pf = 2 * (t + 1) + grp;
        bool pfv = (pf <= j);
        uint4 ka0, ka1, ka2, ka3, va0, va1, va2, va3;
        if (pfv) {
            const char* sK = srcK0 + (size_t)pf * 16384;
            ka0 = *(const uint4*)(sK);
            ka1 = *(const uint4*)(sK + 16);
            ka2 = *(const uint4*)(sK + 32);
            ka3 = *(const uint4*)(sK + 48);
            const char* sV = srcV0 + (size_t)pf * 128;
            va0 = *(const uint4*)(sV);
            va1 = *(const uint4*)(sV + 16);
            va2 = *(const uint4*)(sV + 32);
            va3 = *(const uint4*)(sV + 48);
        }

        int kt = 2 * t + p;
        if (kt <= j) {
            bool diag = (kt == j);
            unsigned int pk[2][4][2];
#pragma unroll
            for (int br = 0; br < 2; ++br) {
                f32x4 s[4] = {};
                __builtin_amdgcn_s_setprio(1);
#pragma unroll
                for (int h = 0; h < 2; ++h) {
#pragma unroll
                    for (int t4 = 0; t4 < 4; ++t4) {
                        int rk = t4 * 16 + q;
                        bf16x8 kf = *(const bf16x8*)(Kb + rk * 256 + ((br * 128 + h * 64 + g4 * 16) ^ ((rk & 7) << 4)));
                        s[t4] = __builtin_amdgcn_mfma_f32_16x16x32_bf16(kf, qf[br][h], s[t4], 0, 0, 0);
                    }
                }
                __builtin_amdgcn_s_setprio(0);
                float sv[16];
                float mx = -1e30f;
#pragma unroll
                for (int t4 = 0; t4 < 4; ++t4)
#pragma unroll
                    for (int r = 0; r < 4; ++r) {
                        float v = s[t4][r] * 0.125f;
                        if (diag) {
                            int kv_g = kt * 64 + t4 * 16 + g4 * 4 + r;
                            if (kv_g > q_g) v = -1e30f;
                        }
                        sv[t4 * 4 + r] = v;
                        mx = fmaxf(mx, v);
                    }
                mx = fmaxf(mx, __shfl_xor(mx, 16));
                mx = fmaxf(mx, __shfl_xor(mx, 32));
                float mn;
                if (__all(mx <= mrun[br] + 8.f)) {
                    mn = mrun[br];
                } else {
                    mn = fmaxf(mrun[br], mx);
                    float sf = __expf(mrun[br] - mn);
                    mrun[br] = mn;
                    lrun[br] *= sf;
#pragma unroll
                    for (int dblk = 0; dblk < 8; ++dblk)
#pragma unroll
                        for (int r = 0; r < 4; ++r)
                            oacc[br][dblk][r] *= sf;
                }
                float pr[16];
                float rs = 0.f;
#pragma unroll
                for (int i = 0; i < 16; ++i) {
                    pr[i] = __expf(sv[i] - mn);
                    rs += pr[i];
                }
                rs += __shfl_xor(rs, 16);
                rs += __shfl_xor(rs, 32);
                lrun[br] += rs;
#pragma unroll
                for (int t4 = 0; t4 < 4; ++t4) {
                    pk[br][t4][0] = pack2bf(pr[t4 * 4 + 0], pr[t4 * 4 + 1]);
                    pk[br][t4][1] = pack2bf(pr[t4 * 4 + 2], pr[t4 * 4 + 3]);
                }
            }
#pragma unroll
            for (int h = 0; h < 2; ++h) {
                bf16x8 pb[2];
                int s0 = q + (((g4 * 2) & 3) << 4);
                int s1 = q + (((g4 * 2 + 1) & 3) << 4);
                int sel = g4 >> 1;
#pragma unroll
                for (int br = 0; br < 2; ++br) {
                    unsigned int m0a = (unsigned int)__shfl((int)pk[br][2 * h][0], s0);
                    unsigned int m0b = (unsigned int)__shfl((int)pk[br][2 * h + 1][0], s0);
                    unsigned int m1a = (unsigned int)__shfl((int)pk[br][2 * h][1], s0);
                    unsigned int m1b = (unsigned int)__shfl((int)pk[br][2 * h + 1][1], s0);
                    unsigned int m2a = (unsigned int)__shfl((int)pk[br][2 * h][0], s1);
                    unsigned int m2b = (unsigned int)__shfl((int)pk[br][2 * h + 1][0], s1);
                    unsigned int m3a = (unsigned int)__shfl((int)pk[br][2 * h][1], s1);
                    unsigned int m3b = (unsigned int)__shfl((int)pk[br][2 * h + 1][1], s1);
                    union { unsigned int uu[4]; bf16x8 v; } pu;
                    pu.uu[0] = sel ? m0b : m0a;
                    pu.uu[1] = sel ? m1b : m1a;
                    pu.uu[2] = sel ? m2b : m2a;
                    pu.uu[3] = sel ? m3b : m3a;
                    pb[br] = pu.v;
                }
                __builtin_amdgcn_s_setprio(1);
#pragma unroll
                for (int dblk = 0; dblk < 8; ++dblk) {
                    int rv = dblk * 16 + q;
                    bf16x8 vf = *(const bf16x8*)(Vb + rv * 128 + ((h * 64 + g4 * 16) ^ ((rv & 7) << 4)));
                    oacc[0][dblk] = __builtin_amdgcn_mfma_f32_16x16x32_bf16(vf, pb[0], oacc[0][dblk], 0, 0, 0);
                    oacc[1][dblk] = __builtin_amdgcn_mfma_f32_16x16x32_bf16(vf, pb[1], oacc[1][dblk], 0, 0, 0);
                }
                __builtin_amdgcn_s_setprio(0);
            }
        }
        __syncthreads();
        if (pfv) {
            *(uint4*)(KwB + oko0) = ka0;
            *(uint4*)(KwB + oko1) = ka1;
            *(uint4*)(KwB + oko2) = ka2;
            *(uint4*)(KwB + oko3) = ka3;
            *(uint4*)(VwB + ovo0) = va0;
            *(uint4*)(VwB + ovo1) = va1;
            *(uint4*)(VwB + ovo2) = va2;
            *(uint4*)(VwB + ovo3) = va3;
        }
        __syncthreads();
    }

    float* Osh = (float*)smem;
    float* Msh = (float*)(smem + 65536);
    if (p == 1) {
        int base = qg * 4096 + l;
#pragma unroll
        for (int br = 0; br < 2; ++br)
#pragma unroll
            for (int dblk = 0; dblk < 8; ++dblk)
#pragma unroll
                for (int r = 0; r < 4; ++r)
                    Osh[base + (br * 32 + dblk * 4 + r) * 64] = oacc[br][dblk][r];
        float4 ml;
        ml.x = mrun[0]; ml.y = lrun[0]; ml.z = mrun[1]; ml.w = lrun[1];
        *(float4*)(Msh + (qg * 64 + l) * 4) = ml;
    }
    __syncthreads();
    if (p == 0) {
        float4 ml = *(const float4*)(Msh + (qg * 64 + l) * 4);
        float m1v[2] = {ml.x, ml.z}, l1v[2] = {ml.y, ml.w};
        float lfin[2], a0[2], a1[2];
#pragma unroll
        for (int br = 0; br < 2; ++br) {
            float mstar = fmaxf(mrun[br], m1v[br]);
            a0[br] = __expf(mrun[br] - mstar);
            a1[br] = __expf(m1v[br] - mstar);
            lfin[br] = a0[br] * lrun[br] + a1[br] * l1v[br];
        }
        int base = qg * 4096 + l;
#pragma unroll
        for (int br = 0; br < 2; ++br)
#pragma unroll
            for (int dblk = 0; dblk < 8; ++dblk)
#pragma unroll
                for (int r = 0; r < 4; ++r)
                    oacc[br][dblk][r] = a0[br] * oacc[br][dblk][r]
                        + a1[br] * Osh[base + (br * 32 + dblk * 4 + r) * 64];

        float pa = lq1[l] * lk1[l];
        float pb2 = lq2[l] * lk2[l];
#pragma unroll
        for (int off = 32; off >= 1; off >>= 1) {
            pa += __shfl_xor(pa, off);
            pb2 += __shfl_xor(pb2, off);
        }
        float lam = __expf(pa) - __expf(pb2) + LAMBDA_INIT_F;

        float att[8][4];
        float sm = 0.f;
        float inv1 = 1.f / lfin[0], inv2 = 1.f / lfin[1];
#pragma unroll
        for (int dblk = 0; dblk < 8; ++dblk)
#pragma unroll
            for (int r = 0; r < 4; ++r) {
                float a = oacc[0][dblk][r] * inv1 - lam * (oacc[1][dblk][r] * inv2);
                att[dblk][r] = a;
                sm += a;
            }
        sm += __shfl_xor(sm, 16);
        sm += __shfl_xor(sm, 32);
        float mean = sm * (1.f / 128.f);
        float sv2 = 0.f;
#pragma unroll
        for (int dblk = 0; dblk < 8; ++dblk)
#pragma unroll
            for (int r = 0; r < 4; ++r) {
                float d = att[dblk][r] - mean;
                sv2 += d * d;
            }
        sv2 += __shfl_xor(sv2, 16);
        sv2 += __shfl_xor(sv2, 32);
        float rstd = rsqrtf(sv2 * (1.f / 128.f) + 1e-5f);

        float* orow = out + ((size_t)b * T_ + q_g) * 128;
#pragma unroll
        for (int dblk = 0; dblk < 8; ++dblk) {
            int d0 = dblk * 16 + g4 * 4;
            float4 o;
            o.x = (att[dblk][0] - mean) * rstd * g_out[d0 + 0] + b_out[d0 + 0];
            o.y = (att[dblk][1] - mean) * rstd * g_out[d0 + 1] + b_out[d0 + 1];
            o.z = (att[dblk][2] - mean) * rstd * g_out[d0 + 2] + b_out[d0 + 2];
            o.w = (att[dblk][3] - mean) * rstd * g_out[d0 + 3] + b_out[d0 + 3];
            *(float4*)(orow + d0) = o;
        }
    }
}

extern "C" void kernel_launch(void* const* d_in, const int* in_sizes, int n_in,
                              void* d_out, int out_size, void* d_ws, size_t ws_size,
                              hipStream_t stream) {
    (void)in_sizes; (void)n_in; (void)out_size; (void)ws_size;
    const float* x = (const float*)d_in[0];
    char* ws = (char*)d_ws;
    unsigned short* wt  = (unsigned short*)ws;                      // 2,359,296 B
    unsigned short* xbf = (unsigned short*)(ws + 2359296);          // 37,748,736 B
    unsigned short* qo  = (unsigned short*)(ws + 40108032);         // 4,718,592 B
    unsigned short* ko  = (unsigned short*)(ws + 44826624);         // 4,718,592 B
    unsigned short* vto = (unsigned short*)(ws + 49545216);         // 4,718,592 B

    hipLaunchKernelGGL(k_wtrans, dim3(288), dim3(256), 0, stream,
        (const float*)d_in[4], (const float*)d_in[5], (const float*)d_in[6],
        (const float*)d_in[1], (const float*)d_in[2], (const float*)d_in[3],
        (const float*)d_in[7], (const float*)d_in[8], (const float*)d_in[9], wt);

    hipLaunchKernelGGL(k_ln, dim3(4608), dim3(256), 0, stream,
        x,
        (const float*)d_in[10], (const float*)d_in[11],
        (const float*)d_in[12], (const float*)d_in[13],
        (const float*)d_in[14], (const float*)d_in[15],
        xbf);

    hipLaunchKernelGGL(k_proj2, dim3(288), dim3(512), 0, stream,
        xbf, wt, qo, ko, vto);

    hipLaunchKernelGGL(k_attn, dim3(288), dim3(512), 0, stream,
        qo, ko, vto,
        (const float*)d_in[18], (const float*)d_in[19],
        (const float*)d_in[20], (const float*)d_in[21],
        (const float*)d_in[16], (const float*)d_in[17],
        (float*)d_out);
}

// Round 6
// 128.119 us; speedup vs baseline: 1.7257x; 1.0237x over previous
//
#include <hip/hip_runtime.h>
#include <hip/hip_bf16.h>
#include <stdint.h>

#define B_ 8
#define T_ 2304
#define DIN 1024
#define LAMBDA_INIT_F 0.6192834728526788f

typedef __bf16 bf16x8 __attribute__((ext_vector_type(8)));
typedef float f32x4 __attribute__((ext_vector_type(4)));

__device__ __forceinline__ unsigned short f2bf(float f) {
    union { float f; unsigned int u; } v; v.f = f;
    unsigned int u = v.u;
    unsigned int r = (u + 0x7FFFu + ((u >> 16) & 1u)) >> 16;
    return (unsigned short)r;
}

__device__ __forceinline__ unsigned int pack2bf(float lo, float hi) {
    return ((unsigned int)f2bf(hi) << 16) | (unsigned int)f2bf(lo);
}

__device__ __forceinline__ float bf2f(unsigned short u) {
    union { unsigned int u; float f; } v; v.u = ((unsigned int)u) << 16;
    return v.f;
}

// ---------------------------------------------------------------------------
// Kernel 1: transpose 9 weight mats (1024x128 f32) -> WT[seg][384][1024] bf16
// ---------------------------------------------------------------------------
__global__ __launch_bounds__(256) void k_wtrans(
    const float* w0, const float* w1, const float* w2,
    const float* w3, const float* w4, const float* w5,
    const float* w6, const float* w7, const float* w8,
    unsigned short* __restrict__ wt)
{
    __shared__ float tile[64][65];
    int bx = blockIdx.x;
    int mat = bx >> 5;
    int tl = bx & 31;
    int tx = tl & 15;
    int ty = tl >> 4;
    const float* srcs[9] = {w0, w1, w2, w3, w4, w5, w6, w7, w8};
    const float* src = srcs[mat];
    int k0 = tx * 64, c0 = ty * 64;
    int t = threadIdx.x;
    int r = t >> 2, cg = (t & 3) << 4;
    const float* p = src + (size_t)(k0 + r) * 128 + c0 + cg;
#pragma unroll
    for (int i = 0; i < 4; ++i) {
        float4 v = *(const float4*)(p + i * 4);
        tile[r][cg + i * 4 + 0] = v.x;
        tile[r][cg + i * 4 + 1] = v.y;
        tile[r][cg + i * 4 + 2] = v.z;
        tile[r][cg + i * 4 + 3] = v.w;
    }
    __syncthreads();
    int seg = mat / 3, m = mat % 3;
    int crow = seg * 384 + m * 128 + c0 + r;
    unsigned short* dst = wt + (size_t)crow * 1024 + k0 + cg;
    __align__(16) unsigned short ob[16];
#pragma unroll
    for (int i = 0; i < 16; ++i) ob[i] = f2bf(tile[cg + i][r]);
    *(uint4*)(dst) = *(const uint4*)(ob);
    *(uint4*)(dst + 8) = *(const uint4*)(ob + 8);
}

// ---------------------------------------------------------------------------
// Kernel 2: streaming LayerNorm: x f32 -> xbf bf16 [18432][1024].
// ---------------------------------------------------------------------------
__global__ __launch_bounds__(256) void k_ln(
    const float* __restrict__ x,
    const float* __restrict__ g_in, const float* __restrict__ b_in,
    const float* __restrict__ g_ss, const float* __restrict__ b_ss,
    const float* __restrict__ g_se, const float* __restrict__ b_se,
    unsigned short* __restrict__ xbf)
{
    int row = (blockIdx.x << 2) + (threadIdx.x >> 6);
    int l = threadIdx.x & 63;
    int t = row % T_;
    const float* gv; const float* bv;
    if (t < 128)       { gv = g_ss; bv = b_ss; }
    else if (t < 2176) { gv = g_in; bv = b_in; }
    else               { gv = g_se; bv = b_se; }
    const float* xp = x + (size_t)row * DIN + l * 4;
    float4 v0 = *(const float4*)(xp);
    float4 v1 = *(const float4*)(xp + 256);
    float4 v2 = *(const float4*)(xp + 512);
    float4 v3 = *(const float4*)(xp + 768);
    float s  = v0.x + v0.y + v0.z + v0.w + v1.x + v1.y + v1.z + v1.w
             + v2.x + v2.y + v2.z + v2.w + v3.x + v3.y + v3.z + v3.w;
    float s2 = v0.x*v0.x + v0.y*v0.y + v0.z*v0.z + v0.w*v0.w
             + v1.x*v1.x + v1.y*v1.y + v1.z*v1.z + v1.w*v1.w
             + v2.x*v2.x + v2.y*v2.y + v2.z*v2.z + v2.w*v2.w
             + v3.x*v3.x + v3.y*v3.y + v3.z*v3.z + v3.w*v3.w;
#pragma unroll
    for (int off = 1; off <= 32; off <<= 1) {
        s  += __shfl_xor(s,  off);
        s2 += __shfl_xor(s2, off);
    }
    float mean = s * (1.f / 1024.f);
    float rstd = rsqrtf(s2 * (1.f / 1024.f) - mean * mean + 1e-5f);
    unsigned short* op = xbf + (size_t)row * DIN + l * 4;
    const float* gp = gv + l * 4;
    const float* bp = bv + l * 4;
#pragma unroll
    for (int k = 0; k < 4; ++k) {
        float4 vv = (k == 0) ? v0 : (k == 1) ? v1 : (k == 2) ? v2 : v3;
        float4 gk = *(const float4*)(gp + k * 256);
        float4 bk = *(const float4*)(bp + k * 256);
        uint2 o;
        o.x = pack2bf((vv.x - mean) * rstd * gk.x + bk.x,
                      (vv.y - mean) * rstd * gk.y + bk.y);
        o.y = pack2bf((vv.z - mean) * rstd * gk.z + bk.z,
                      (vv.w - mean) * rstd * gk.w + bk.w);
        *(uint2*)(op + k * 256) = o;
    }
}

// ---------------------------------------------------------------------------
// Kernel 3: pure bf16 GEMM: C[18432][384] = xbf @ wt[seg]^T. (unchanged R5)
// ---------------------------------------------------------------------------
__global__ __launch_bounds__(512, 4) void k_proj2(
    const unsigned short* __restrict__ xbf,
    const unsigned short* __restrict__ wt,
    unsigned short* __restrict__ qo,
    unsigned short* __restrict__ ko,
    unsigned short* __restrict__ vto)
{
    __shared__ __align__(16) char smem[81920];

    int bid = blockIdx.x;
    int mt = bid >> 1, ch = bid & 1;
    int bb = mt / 18, tt = mt % 18;
    int seg = (tt == 0) ? 0 : ((tt < 17) ? 1 : 2);
    size_t arow0 = (size_t)mt * 128;
    int ncol0 = ch * 192;
    int wrow0 = seg * 384 + ncol0;

    int tid = threadIdx.x;
    int w = tid >> 6, l = tid & 63;
    int wr = w >> 2, wc = w & 3;
    int g4 = l >> 4, cr = l & 15;

    int rA0 = tid >> 3, cS = (tid & 7) << 4;
    const char* srcA0 = (const char*)xbf + (arow0 + rA0) * 2048 + cS;
    const char* srcA1 = srcA0 + (size_t)64 * 2048;
    int dA0 = rA0 * 128 + (cS ^ ((rA0 & 7) << 4));
    int dA1 = dA0 + 64 * 128;
    const char* srcW0 = (const char*)wt + (size_t)(wrow0 + rA0) * 2048 + cS;
    const char* srcW1 = srcW0 + (size_t)64 * 2048;
    const char* srcW2 = srcW0 + (size_t)128 * 2048;
    int dW0 = dA0, dW1 = dA0 + 64 * 128, dW2 = dA0 + 128 * 128;

    {
        uint4 a0 = *(const uint4*)srcA0;
        uint4 a1 = *(const uint4*)srcA1;
        uint4 w0 = *(const uint4*)srcW0;
        uint4 w1 = *(const uint4*)srcW1;
        uint4 w2 = *(const uint4*)srcW2;
        *(uint4*)(smem + dA0) = a0;
        *(uint4*)(smem + dA1) = a1;
        *(uint4*)(smem + 32768 + dW0) = w0;
        *(uint4*)(smem + 32768 + dW1) = w1;
        *(uint4*)(smem + 32768 + dW2) = w2;
    }
    __syncthreads();

    f32x4 acc[4][3] = {};
    for (int ks = 0; ks < 16; ++ks) {
        bool pf = (ks < 15);
        uint4 pa0, pa1, pw0, pw1, pw2;
        if (pf) {
            size_t o = (size_t)(ks + 1) * 128;
            pa0 = *(const uint4*)(srcA0 + o);
            pa1 = *(const uint4*)(srcA1 + o);
            pw0 = *(const uint4*)(srcW0 + o);
            pw1 = *(const uint4*)(srcW1 + o);
            pw2 = *(const uint4*)(srcW2 + o);
        }
        const char* Ab = smem + (ks & 1) * 16384;
        const char* Wb = smem + 32768 + (ks & 1) * 24576;
        __builtin_amdgcn_s_setprio(1);
#pragma unroll
        for (int kk = 0; kk < 2; ++kk) {
            int kb = kk * 64 + g4 * 16;
            bf16x8 af[4];
#pragma unroll
            for (int r4 = 0; r4 < 4; ++r4) {
                int rr = wr * 64 + r4 * 16 + cr;
                af[r4] = *(const bf16x8*)(Ab + rr * 128 + (kb ^ ((rr & 7) << 4)));
            }
            bf16x8 bfr[3];
#pragma unroll
            for (int nt = 0; nt < 3; ++nt) {
                int c = wc * 48 + nt * 16 + cr;
                bfr[nt] = *(const bf16x8*)(Wb + c * 128 + (kb ^ ((c & 7) << 4)));
            }
#pragma unroll
            for (int r4 = 0; r4 < 4; ++r4)
#pragma unroll
                for (int nt = 0; nt < 3; ++nt)
                    acc[r4][nt] = __builtin_amdgcn_mfma_f32_16x16x32_bf16(af[r4], bfr[nt], acc[r4][nt], 0, 0, 0);
        }
        __builtin_amdgcn_s_setprio(0);
        __syncthreads();
        if (pf) {
            char* An = smem + ((ks + 1) & 1) * 16384;
            char* Wn = smem + 32768 + ((ks + 1) & 1) * 24576;
            *(uint4*)(An + dA0) = pa0;
            *(uint4*)(An + dA1) = pa1;
            *(uint4*)(Wn + dW0) = pw0;
            *(uint4*)(Wn + dW1) = pw1;
            *(uint4*)(Wn + dW2) = pw2;
        }
        __syncthreads();
    }

#pragma unroll
    for (int r4 = 0; r4 < 4; ++r4) {
        size_t grow = arow0 + wr * 64 + r4 * 16 + g4 * 4;
#pragma unroll
        for (int nt = 0; nt < 3; ++nt) {
            int c = ncol0 + wc * 48 + nt * 16 + cr;
            f32x4 a = acc[r4][nt];
            if (c < 128) {
#pragma unroll
                for (int g = 0; g < 4; ++g)
                    qo[(grow + g) * 128 + c] = f2bf(a[g]);
            } else if (c < 256) {
#pragma unroll
                for (int g = 0; g < 4; ++g)
                    ko[(grow + g) * 128 + (c - 128)] = f2bf(a[g]);
            } else {
                int cv = c - 256;
                int trow = tt * 128 + wr * 64 + r4 * 16 + g4 * 4;
                uint2 o;
                o.x = pack2bf(a[0], a[1]);
                o.y = pack2bf(a[2], a[3]);
                *(uint2*)(vto + ((size_t)bb * 128 + cv) * T_ + trow) = o;
            }
        }
    }
}

// ---------------------------------------------------------------------------
// Kernel 4: causal diff flash-attention, KV-SPLIT (chunks of 12 kv-tiles).
// Split tiles (j>=12) emit partial (m,l,O-bf16); j<12 write final output.
// ---------------------------------------------------------------------------
__global__ __launch_bounds__(512, 2) void k_attn(
    const unsigned short* __restrict__ qp_,
    const unsigned short* __restrict__ kp_,
    const unsigned short* __restrict__ vp_,
    const float* __restrict__ lq1, const float* __restrict__ lq2,
    const float* __restrict__ lk1, const float* __restrict__ lk2,
    const float* __restrict__ g_out, const float* __restrict__ b_out,
    unsigned short* __restrict__ opart,
    float* __restrict__ mlpart,
    float* __restrict__ out)
{
    __shared__ __align__(16) char smem[69632];

    int bid = blockIdx.x;
    int b = bid & 7;
    int u = 71 - (bid >> 3);     // descending work order
    int j, ci;
    if (u < 12)      { j = u; ci = 0; }
    else if (u < 36) { int v = u - 12; j = 12 + (v >> 1); ci = v & 1; }
    else             { int v = u - 36; j = 24 + v / 3; ci = v % 3; }
    int nch = (j + 12) / 12;
    int c0 = ci * 12;
    int ntile = min(12, j + 1 - c0);
    int t0 = j * 64;

    int tid = threadIdx.x;
    int w8 = tid >> 6;
    int qg = w8 & 3;
    int p  = w8 >> 2;
    int l = tid & 63;
    int g4 = l >> 4, q = l & 15;
    int q_g = t0 + qg * 16 + q;
    int grp = tid >> 8;
    int uu = tid & 255;

    int rK = uu >> 2, cK = (uu & 3) << 6;
    const char* srcK0 = (const char*)(kp_ + ((size_t)b * T_ + rK) * 128) + cK;
    int rV = uu >> 1, cV = (uu & 1) << 6;
    const char* srcV0 = (const char*)(vp_ + ((size_t)b * 128 + rV) * T_) + cV;
    int swK = (rK & 7) << 4;
    char* KwB = smem + grp * 16384 + rK * 256;
    int oko0 = (cK +  0) ^ swK, oko1 = (cK + 16) ^ swK;
    int oko2 = (cK + 32) ^ swK, oko3 = (cK + 48) ^ swK;
    int swV = (rV & 7) << 4;
    char* VwB = smem + 32768 + grp * 16384 + rV * 128;
    int ovo0 = (cV +  0) ^ swV, ovo1 = (cV + 16) ^ swV;
    int ovo2 = (cV + 32) ^ swV, ovo3 = (cV + 48) ^ swV;

    bf16x8 qf[2][2];
#pragma unroll
    for (int br = 0; br < 2; ++br)
#pragma unroll
        for (int h = 0; h < 2; ++h)
            qf[br][h] = *(const bf16x8*)(qp_ + ((size_t)b * T_ + q_g) * 128 + br * 64 + h * 32 + g4 * 8);

    if (grp < ntile) {
        const char* sK = srcK0 + (size_t)(c0 + grp) * 16384;
        uint4 ka0 = *(const uint4*)(sK);
        uint4 ka1 = *(const uint4*)(sK + 16);
        uint4 ka2 = *(const uint4*)(sK + 32);
        uint4 ka3 = *(const uint4*)(sK + 48);
        const char* sV = srcV0 + (size_t)(c0 + grp) * 128;
        uint4 va0 = *(const uint4*)(sV);
        uint4 va1 = *(const uint4*)(sV + 16);
        uint4 va2 = *(const uint4*)(sV + 32);
        uint4 va3 = *(const uint4*)(sV + 48);
        *(uint4*)(KwB + oko0) = ka0;
        *(uint4*)(KwB + oko1) = ka1;
        *(uint4*)(KwB + oko2) = ka2;
        *(uint4*)(KwB + oko3) = ka3;
        *(uint4*)(VwB + ovo0) = va0;
        *(uint4*)(VwB + ovo1) = va1;
        *(uint4*)(VwB + ovo2) = va2;
        *(uint4*)(VwB + ovo3) = va3;
    }
    __syncthreads();

    float mrun[2] = {-1e30f, -1e30f};
    float lrun[2] = {0.f, 0.f};
    f32x4 oacc[2][8] = {};
    const char* Kb = smem + p * 16384;
    const char* Vb = smem + 32768 + p * 16384;

    int nph = (ntile + 1) >> 1;
    for (int t = 0; t < nph; ++t) {
        int lpf = 2 * (t + 1) + grp;
        bool pfv = (lpf < ntile);
        uint4 ka0, ka1, ka2, ka3, va0, va1, va2, va3;
        if (pfv) {
            const char* sK = srcK0 + (size_t)(c0 + lpf) * 16384;
            ka0 = *(const uint4*)(sK);
            ka1 = *(const uint4*)(sK + 16);
            ka2 = *(const uint4*)(sK + 32);
            ka3 = *(const uint4*)(sK + 48);
            const char* sV = srcV0 + (size_t)(c0 + lpf) * 128;
            va0 = *(const uint4*)(sV);
            va1 = *(const uint4*)(sV + 16);
            va2 = *(const uint4*)(sV + 32);
            va3 = *(const uint4*)(sV + 48);
        }

        int lt = 2 * t + p;
        if (lt < ntile) {
            int kt = c0 + lt;
            bool diag = (kt == j);
            unsigned int pk[2][4][2];
#pragma unroll
            for (int br = 0; br < 2; ++br) {
                f32x4 s[4] = {};
                __builtin_amdgcn_s_setprio(1);
#pragma unroll
                for (int h = 0; h < 2; ++h) {
#pragma unroll
                    for (int t4 = 0; t4 < 4; ++t4) {
                        int rk = t4 * 16 + q;
                        bf16x8 kf = *(const bf16x8*)(Kb + rk * 256 + ((br * 128 + h * 64 + g4 * 16) ^ ((rk & 7) << 4)));
                        s[t4] = __builtin_amdgcn_mfma_f32_16x16x32_bf16(kf, qf[br][h], s[t4], 0, 0, 0);
                    }
                }
                __builtin_amdgcn_s_setprio(0);
                float sv[16];
                float mx = -1e30f;
#pragma unroll
                for (int t4 = 0; t4 < 4; ++t4)
#pragma unroll
                    for (int r = 0; r < 4; ++r) {
                        float v = s[t4][r] * 0.125f;
                        if (diag) {
                            int kv_g = kt * 64 + t4 * 16 + g4 * 4 + r;
                            if (kv_g > q_g) v = -1e30f;
                        }
                        sv[t4 * 4 + r] = v;
                        mx = fmaxf(mx, v);
                    }
                mx = fmaxf(mx, __shfl_xor(mx, 16));
                mx = fmaxf(mx, __shfl_xor(mx, 32));
                float mn;
                if (__all(mx <= mrun[br] + 8.f)) {
                    mn = mrun[br];
                } else {
                    mn = fmaxf(mrun[br], mx);
                    float sf = __expf(mrun[br] - mn);
                    mrun[br] = mn;
                    lrun[br] *= sf;
#pragma unroll
                    for (int dblk = 0; dblk < 8; ++dblk)
#pragma unroll
                        for (int r = 0; r < 4; ++r)
                            oacc[br][dblk][r] *= sf;
                }
                float pr[16];
                float rs = 0.f;
#pragma unroll
                for (int i = 0; i < 16; ++i) {
                    pr[i] = __expf(sv[i] - mn);
                    rs += pr[i];
                }
                rs += __shfl_xor(rs, 16);
                rs += __shfl_xor(rs, 32);
                lrun[br] += rs;
#pragma unroll
                for (int t4 = 0; t4 < 4; ++t4) {
                    pk[br][t4][0] = pack2bf(pr[t4 * 4 + 0], pr[t4 * 4 + 1]);
                    pk[br][t4][1] = pack2bf(pr[t4 * 4 + 2], pr[t4 * 4 + 3]);
                }
            }
#pragma unroll
            for (int h = 0; h < 2; ++h) {
                bf16x8 pb[2];
                int s0 = q + (((g4 * 2) & 3) << 4);
                int s1 = q + (((g4 * 2 + 1) & 3) << 4);
                int sel = g4 >> 1;
#pragma unroll
                for (int br = 0; br < 2; ++br) {
                    unsigned int m0a = (unsigned int)__shfl((int)pk[br][2 * h][0], s0);
                    unsigned int m0b = (unsigned int)__shfl((int)pk[br][2 * h + 1][0], s0);
                    unsigned int m1a = (unsigned int)__shfl((int)pk[br][2 * h][1], s0);
                    unsigned int m1b = (unsigned int)__shfl((int)pk[br][2 * h + 1][1], s0);
                    unsigned int m2a = (unsigned int)__shfl((int)pk[br][2 * h][0], s1);
                    unsigned int m2b = (unsigned int)__shfl((int)pk[br][2 * h + 1][0], s1);
                    unsigned int m3a = (unsigned int)__shfl((int)pk[br][2 * h][1], s1);
                    unsigned int m3b = (unsigned int)__shfl((int)pk[br][2 * h + 1][1], s1);
                    union { unsigned int uv[4]; bf16x8 v; } pu;
                    pu.uv[0] = sel ? m0b : m0a;
                    pu.uv[1] = sel ? m1b : m1a;
                    pu.uv[2] = sel ? m2b : m2a;
                    pu.uv[3] = sel ? m3b : m3a;
                    pb[br] = pu.v;
                }
                __builtin_amdgcn_s_setprio(1);
#pragma unroll
                for (int dblk = 0; dblk < 8; ++dblk) {
                    int rv = dblk * 16 + q;
                    bf16x8 vf = *(const bf16x8*)(Vb + rv * 128 + ((h * 64 + g4 * 16) ^ ((rv & 7) << 4)));
                    oacc[0][dblk] = __builtin_amdgcn_mfma_f32_16x16x32_bf16(vf, pb[0], oacc[0][dblk], 0, 0, 0);
                    oacc[1][dblk] = __builtin_amdgcn_mfma_f32_16x16x32_bf16(vf, pb[1], oacc[1][dblk], 0, 0, 0);
                }
                __builtin_amdgcn_s_setprio(0);
            }
        }
        __syncthreads();
        if (pfv) {
            *(uint4*)(KwB + oko0) = ka0;
            *(uint4*)(KwB + oko1) = ka1;
            *(uint4*)(KwB + oko2) = ka2;
            *(uint4*)(KwB + oko3) = ka3;
            *(uint4*)(VwB + ovo0) = va0;
            *(uint4*)(VwB + ovo1) = va1;
            *(uint4*)(VwB + ovo2) = va2;
            *(uint4*)(VwB + ovo3) = va3;
        }
        __syncthreads();
    }

    // ---- merge parity halves in LDS ----
    float* Osh = (float*)smem;
    float* Msh = (float*)(smem + 65536);
    if (p == 1) {
        int base = qg * 4096 + l;
#pragma unroll
        for (int br = 0; br < 2; ++br)
#pragma unroll
            for (int dblk = 0; dblk < 8; ++dblk)
#pragma unroll
                for (int r = 0; r < 4; ++r)
                    Osh[base + (br * 32 + dblk * 4 + r) * 64] = oacc[br][dblk][r];
        float4 ml;
        ml.x = mrun[0]; ml.y = lrun[0]; ml.z = mrun[1]; ml.w = lrun[1];
        *(float4*)(Msh + (qg * 64 + l) * 4) = ml;
    }
    __syncthreads();
    if (p == 0) {
        float4 ml = *(const float4*)(Msh + (qg * 64 + l) * 4);
        float m1v[2] = {ml.x, ml.z}, l1v[2] = {ml.y, ml.w};
        float lfin[2], mst[2];
#pragma unroll
        for (int br = 0; br < 2; ++br) {
            float mstar = fmaxf(mrun[br], m1v[br]);
            float a0 = __expf(mrun[br] - mstar);
            float a1 = __expf(m1v[br] - mstar);
            lfin[br] = a0 * lrun[br] + a1 * l1v[br];
            mst[br] = mstar;
            int base = qg * 4096 + l;
#pragma unroll
            for (int dblk = 0; dblk < 8; ++dblk)
#pragma unroll
                for (int r = 0; r < 4; ++r)
                    oacc[br][dblk][r] = a0 * oacc[br][dblk][r]
                        + a1 * Osh[base + (br * 32 + dblk * 4 + r) * 64];
        }

        int row = qg * 16 + q;
        if (nch == 1) {
            // final epilogue
            float pa = lq1[l] * lk1[l];
            float pb2 = lq2[l] * lk2[l];
#pragma unroll
            for (int off = 32; off >= 1; off >>= 1) {
                pa += __shfl_xor(pa, off);
                pb2 += __shfl_xor(pb2, off);
            }
            float lam = __expf(pa) - __expf(pb2) + LAMBDA_INIT_F;

            float att[8][4];
            float sm = 0.f;
            float inv1 = 1.f / lfin[0], inv2 = 1.f / lfin[1];
#pragma unroll
            for (int dblk = 0; dblk < 8; ++dblk)
#pragma unroll
                for (int r = 0; r < 4; ++r) {
                    float a = oacc[0][dblk][r] * inv1 - lam * (oacc[1][dblk][r] * inv2);
                    att[dblk][r] = a;
                    sm += a;
                }
            sm += __shfl_xor(sm, 16);
            sm += __shfl_xor(sm, 32);
            float mean = sm * (1.f / 128.f);
            float sv2 = 0.f;
#pragma unroll
            for (int dblk = 0; dblk < 8; ++dblk)
#pragma unroll
                for (int r = 0; r < 4; ++r) {
                    float d = att[dblk][r] - mean;
                    sv2 += d * d;
                }
            sv2 += __shfl_xor(sv2, 16);
            sv2 += __shfl_xor(sv2, 32);
            float rstd = rsqrtf(sv2 * (1.f / 128.f) + 1e-5f);

            float* orow = out + ((size_t)b * T_ + q_g) * 128;
#pragma unroll
            for (int dblk = 0; dblk < 8; ++dblk) {
                int d0 = dblk * 16 + g4 * 4;
                float4 o;
                o.x = (att[dblk][0] - mean) * rstd * g_out[d0 + 0] + b_out[d0 + 0];
                o.y = (att[dblk][1] - mean) * rstd * g_out[d0 + 1] + b_out[d0 + 1];
                o.z = (att[dblk][2] - mean) * rstd * g_out[d0 + 2] + b_out[d0 + 2];
                o.w = (att[dblk][3] - mean) * rstd * g_out[d0 + 3] + b_out[d0 + 3];
                *(float4*)(orow + d0) = o;
            }
        } else {
            // write partials: O bf16 + (m,l) f32
            int slot = (b * 36 + j) * 3 + ci;
            char* ob = (char*)opart + (size_t)slot * 32768;
#pragma unroll
            for (int br = 0; br < 2; ++br) {
#pragma unroll
                for (int dblk = 0; dblk < 8; ++dblk) {
                    uint2 o;
                    o.x = pack2bf(oacc[br][dblk][0], oacc[br][dblk][1]);
                    o.y = pack2bf(oacc[br][dblk][2], oacc[br][dblk][3]);
                    *(uint2*)(ob + br * 16384 + row * 256 + (dblk * 16 + g4 * 4) * 2) = o;
                }
                float2 mlv;
                mlv.x = mst[br];
                mlv.y = lfin[br];
                *(float2*)(mlpart + ((size_t)slot * 128 + br * 64 + row) * 2) = mlv;
            }
        }
    }
}

// ---------------------------------------------------------------------------
// Kernel 5: merge 2-3 KV-split partials per (b, j>=12) tile + lambda-diff +
// output LN. 512 threads: row = tid>>3 (64 rows), 16 d per thread.
// ---------------------------------------------------------------------------
__global__ __launch_bounds__(512) void k_merge(
    const unsigned short* __restrict__ opart,
    const float* __restrict__ mlpart,
    const float* __restrict__ lq1, const float* __restrict__ lq2,
    const float* __restrict__ lk1, const float* __restrict__ lk2,
    const float* __restrict__ g_out, const float* __restrict__ b_out,
    float* __restrict__ out)
{
    int bid = blockIdx.x;
    int b = bid & 7;
    int j = 12 + (bid >> 3);
    int nch = (j + 12) / 12;   // 2 or 3
    int tid = threadIdx.x;
    int row = tid >> 3;
    int d0 = (tid & 7) * 16;
    int l = tid & 63;

    float pa = lq1[l] * lk1[l];
    float pb = lq2[l] * lk2[l];
#pragma unroll
    for (int off = 32; off >= 1; off >>= 1) {
        pa += __shfl_xor(pa, off);
        pb += __shfl_xor(pb, off);
    }
    float lam = __expf(pa) - __expf(pb) + LAMBDA_INIT_F;

    int slotb = (b * 36 + j) * 3;
    float res[2][16];
#pragma unroll
    for (int br = 0; br < 2; ++br) {
        float m0 = mlpart[((size_t)(slotb + 0) * 128 + br * 64 + row) * 2];
        float l0 = mlpart[((size_t)(slotb + 0) * 128 + br * 64 + row) * 2 + 1];
        float m1 = mlpart[((size_t)(slotb + 1) * 128 + br * 64 + row) * 2];
        float l1 = mlpart[((size_t)(slotb + 1) * 128 + br * 64 + row) * 2 + 1];
        float m2 = -1e30f, l2 = 0.f;
        if (nch == 3) {
            m2 = mlpart[((size_t)(slotb + 2) * 128 + br * 64 + row) * 2];
            l2 = mlpart[((size_t)(slotb + 2) * 128 + br * 64 + row) * 2 + 1];
        }
        float mstar = fmaxf(fmaxf(m0, m1), m2);
        float w0 = __expf(m0 - mstar);
        float w1 = __expf(m1 - mstar);
        float w2 = (nch == 3) ? __expf(m2 - mstar) : 0.f;
        float lsum = w0 * l0 + w1 * l1 + w2 * l2;

        float acc[16] = {};
#pragma unroll
        for (int c = 0; c < 3; ++c) {
            if (c >= nch) break;
            float wc = (c == 0) ? w0 : (c == 1) ? w1 : w2;
            const char* ob = (const char*)opart + (size_t)(slotb + c) * 32768
                           + br * 16384 + row * 256 + d0 * 2;
            uint4 v0 = *(const uint4*)(ob);
            uint4 v1 = *(const uint4*)(ob + 16);
            const unsigned int vv[8] = {v0.x, v0.y, v0.z, v0.w, v1.x, v1.y, v1.z, v1.w};
#pragma unroll
            for (int i = 0; i < 8; ++i) {
                acc[i * 2]     += wc * bf2f((unsigned short)(vv[i] & 0xFFFF));
                acc[i * 2 + 1] += wc * bf2f((unsigned short)(vv[i] >> 16));
            }
        }
        float inv = 1.f / lsum;
#pragma unroll
        for (int i = 0; i < 16; ++i) res[br][i] = acc[i] * inv;
    }

    float att[16];
    float sm = 0.f;
#pragma unroll
    for (int i = 0; i < 16; ++i) {
        att[i] = res[0][i] - lam * res[1][i];
        sm += att[i];
    }
    sm += __shfl_xor(sm, 1);
    sm += __shfl_xor(sm, 2);
    sm += __shfl_xor(sm, 4);
    float mean = sm * (1.f / 128.f);
    float sv2 = 0.f;
#pragma unroll
    for (int i = 0; i < 16; ++i) {
        float d = att[i] - mean;
        sv2 += d * d;
    }
    sv2 += __shfl_xor(sv2, 1);
    sv2 += __shfl_xor(sv2, 2);
    sv2 += __shfl_xor(sv2, 4);
    float rstd = rsqrtf(sv2 * (1.f / 128.f) + 1e-5f);

    float* orow = out + ((size_t)b * T_ + j * 64 + row) * 128 + d0;
#pragma unroll
    for (int k = 0; k < 4; ++k) {
        float4 o;
        o.x = (att[k * 4 + 0] - mean) * rstd * g_out[d0 + k * 4 + 0] + b_out[d0 + k * 4 + 0];
        o.y = (att[k * 4 + 1] - mean) * rstd * g_out[d0 + k * 4 + 1] + b_out[d0 + k * 4 + 1];
        o.z = (att[k * 4 + 2] - mean) * rstd * g_out[d0 + k * 4 + 2] + b_out[d0 + k * 4 + 2];
        o.w = (att[k * 4 + 3] - mean) * rstd * g_out[d0 + k * 4 + 3] + b_out[d0 + k * 4 + 3];
        *(float4*)(orow + k * 4) = o;
    }
}

extern "C" void kernel_launch(void* const* d_in, const int* in_sizes, int n_in,
                              void* d_out, int out_size, void* d_ws, size_t ws_size,
                              hipStream_t stream) {
    (void)in_sizes; (void)n_in; (void)out_size; (void)ws_size;
    const float* x = (const float*)d_in[0];
    char* ws = (char*)d_ws;
    unsigned short* wt  = (unsigned short*)ws;                      // 2,359,296 B
    unsigned short* xbf = (unsigned short*)(ws + 2359296);          // 37,748,736 B
    unsigned short* qo  = (unsigned short*)(ws + 40108032);         // 4,718,592 B
    unsigned short* ko  = (unsigned short*)(ws + 44826624);         // 4,718,592 B
    unsigned short* vto = (unsigned short*)(ws + 49545216);         // 4,718,592 B
    // partials alias the xbf region (xbf is dead after k_proj2):
    unsigned short* opart = (unsigned short*)(ws + 2359296);        // 864*32768 = 28,311,552 B
    float*          mlpart = (float*)(ws + 2359296 + 28311552);     // 864*1024  =    884,736 B

    hipLaunchKernelGGL(k_wtrans, dim3(288), dim3(256), 0, stream,
        (const float*)d_in[4], (const float*)d_in[5], (const float*)d_in[6],
        (const float*)d_in[1], (const float*)d_in[2], (const float*)d_in[3],
        (const float*)d_in[7], (const float*)d_in[8], (const float*)d_in[9], wt);

    hipLaunchKernelGGL(k_ln, dim3(4608), dim3(256), 0, stream,
        x,
        (const float*)d_in[10], (const float*)d_in[11],
        (const float*)d_in[12], (const float*)d_in[13],
        (const float*)d_in[14], (const float*)d_in[15],
        xbf);

    hipLaunchKernelGGL(k_proj2, dim3(288), dim3(512), 0, stream,
        xbf, wt, qo, ko, vto);

    hipLaunchKernelGGL(k_attn, dim3(576), dim3(512), 0, stream,
        qo, ko, vto,
        (const float*)d_in[18], (const float*)d_in[19],
        (const float*)d_in[20], (const float*)d_in[21],
        (const float*)d_in[16], (const float*)d_in[17],
        opart, mlpart,
        (float*)d_out);

    hipLaunchKernelGGL(k_merge, dim3(192), dim3(512), 0, stream,
        opart, mlpart,
        (const float*)d_in[18], (const float*)d_in[19],
        (const float*)d_in[20], (const float*)d_in[21],
        (const float*)d_in[16], (const float*)d_in[17],
        (float*)d_out);
}